// Round 6
// baseline (997.556 us; speedup 1.0000x reference)
//
#include <hip/hip_runtime.h>
#include <hip/hip_cooperative_groups.h>
#include <hip/hip_bf16.h>
#include <math.h>
#include <stddef.h>

namespace cg = cooperative_groups;

#define BN 131072
#define CN 40
#define NTOT (BN * CN)
#define MASKW (BN / 64)   // 2048 uint64 words per column
#define NBLK 1024         // k_fuse grid
#define NCHUNK 8          // selection chunks per column
#define CROWS (BN / NCHUNK)   // 16384 rows per chunk

// Workspace layout. Zeroed region = [acc .. ghist2] (one memset).
// u.mask is union'd with k_fuse partials: fuse writes parts -> coop P0 reads
// -> coop P3 overwrites mask.
struct Ws {
    double acc;
    double pad0;
    unsigned ghist0[CN][4096];         // level-0 hist (digit = mk>>18, <=4064)
    unsigned ghist1[CN][1024];         // level-1 hist (digit = (mk>>8)&0x3FF)
    unsigned ghist2[CN][256];          // level-2 hist (digit = mk&0xFF)
    // ---- not zeroed below ----
    double lossc[CN];                  // round-1 fallback only
    int    posc[CN];                   // round-1 fallback only
    float drate[CN];
    float majl[CN];
    float minl[CN];
    float w_hard[CN];
    float w_easy[CN];
    int   hardf[CN];
    int   kdrop[CN];
    int   minpos[CN];
    union {
        unsigned long long mask[CN][MASKW];                           // 640 KB
        struct { float lpart[CN][NBLK]; int ppart[CN][NBLK]; } parts; // 320 KB
    } u;
    unsigned long long eqmask[CN][MASKW];  // ==T ballot masks (640 KB)
    unsigned keys[CN][BN];                 // transposed packed (g_bits<<1)|t
};

__device__ __forceinline__ float bce_f(float x, float t) {
    float e = __expf(-fabsf(x));
    return fmaxf(x, 0.0f) + __logf(1.0f + e) - x * t;
}
__device__ __forceinline__ float g_f(float x, float t) {
    float e   = __expf(-fabsf(x));
    float inv = __builtin_amdgcn_rcpf(1.0f + e);
    float s   = (x >= 0.0f) ? inv : e * inv;
    return fabsf(s - t);
}
// fused fast version: one exp for both bce and g
__device__ __forceinline__ void bce_g(float x, float t, float& bce, float& g) {
    float e   = __expf(-fabsf(x));
    bce       = fmaxf(x, 0.0f) + __logf(1.0f + e) - x * t;
    float inv = __builtin_amdgcn_rcpf(1.0f + e);
    float s   = (x >= 0.0f) ? inv : e * inv;   // stable sigmoid
    g         = fabsf(s - t);
}
__device__ __forceinline__ unsigned masked_key(unsigned key, unsigned majb) {
    return ((key & 1u) == majb) ? (key >> 1) : 0xFFFFFFFFu;
}
__device__ __forceinline__ bool col_active(const Ws* ws, int c) {
    return (ws->kdrop[c] > 0) && (ws->hardf[c] == 0);
}

// Block-wide pick: first bin where cumulative count >= krem.
// 1024 threads, PER bins/thread. out2[0]=bin, out2[1]=krem-prefix(bin).
template<int PER, int NBINS>
__device__ __forceinline__ void scan_pick(const unsigned* __restrict__ gh,
                                          unsigned krem,
                                          unsigned* wsum /*[16]*/,
                                          unsigned* out2 /*[2]*/) {
    int tid = threadIdx.x, lane = tid & 63, w = tid >> 6;
    unsigned v[PER];
    unsigned s = 0;
    #pragma unroll
    for (int i = 0; i < PER; ++i) {
        int idx = tid * PER + i;
        v[i] = (idx < NBINS) ? gh[idx] : 0u;
        s += v[i];
    }
    unsigned isc = s;
    #pragma unroll
    for (int d = 1; d < 64; d <<= 1) {
        unsigned o = __shfl_up(isc, (unsigned)d, 64);
        if (lane >= d) isc += o;
    }
    if (lane == 63) wsum[w] = isc;
    __syncthreads();
    unsigned wpre = 0;
    #pragma unroll
    for (int j = 0; j < 16; ++j) wpre += (j < w) ? wsum[j] : 0u;
    unsigned inc = wpre + isc, prev = inc - s;
    if (prev < krem && inc >= krem) {
        unsigned cum = prev;
        #pragma unroll
        for (int i = 0; i < PER; ++i) {
            if (cum < krem && cum + v[i] >= krem) {
                out2[0] = (unsigned)(tid * PER + i);
                out2[1] = krem - cum;
            }
            cum += v[i];
        }
    }
    __syncthreads();
}

// ================================================================ kernel A
// Fused: per-column bce sum + pos count + LDS-tiled transpose of packed keys.
// XCD-swizzled tile mapping for L2-local selection reads.
__global__ __launch_bounds__(640) void k_fuse(const float* __restrict__ pred,
                                              const float* __restrict__ tgt,
                                              Ws* __restrict__ ws) {
    __shared__ unsigned shk[128 * 41];   // +1 pad kills stride-40 bank conflict
    __shared__ float sl[CN];
    __shared__ int   sp[CN];
    int tid = threadIdx.x;
    if (tid < CN) { sl[tid] = 0.0f; sp[tid] = 0; }
    __syncthreads();

    int  tile  = (blockIdx.x & 7) * 128 + (blockIdx.x >> 3);   // XCD swizzle
    long tile0 = (long)tile * 5120;
    int  c0    = (tid * 4) % 40;         // fixed 4 columns per thread
    float accl[4] = {0, 0, 0, 0};
    int   cntp[4] = {0, 0, 0, 0};

    #pragma unroll
    for (int j = 0; j < 2; ++j) {
        int e = j * 2560 + tid * 4;
        const float4 p = *(const float4*)(pred + tile0 + e);
        const float4 t = *(const float4*)(tgt + tile0 + e);
        int r = e / 40;
        #pragma unroll
        for (int u = 0; u < 4; ++u) {
            float pu = (&p.x)[u], tu = (&t.x)[u];
            float bce, g;
            bce_g(pu, tu, bce, g);
            accl[u] += bce;
            int tb = (tu != 0.0f) ? 1 : 0;
            cntp[u] += tb;
            shk[r * 41 + c0 + u] = (__float_as_uint(g) << 1) | (unsigned)tb;
        }
    }
    #pragma unroll
    for (int u = 0; u < 4; ++u) {
        atomicAdd(&sl[c0 + u], accl[u]);
        atomicAdd(&sp[c0 + u], cntp[u]);
    }
    __syncthreads();

    int w = tid / 128, r = tid % 128;
    int row0 = tile * 128;
    #pragma unroll
    for (int cc = 0; cc < 8; ++cc) {
        int c = w * 8 + cc;
        ws->keys[c][row0 + r] = shk[r * 41 + c];
    }
    if (tid < CN) {
        ws->u.parts.lpart[tid][blockIdx.x] = sl[tid];
        ws->u.parts.ppart[tid][blockIdx.x] = sp[tid];
    }
}

// ================================================================ kernel COOP
// One cooperative kernel: params + 3-level radix hist + mask + tie + final
// weighted sum + output write. grid = 320 x 1024, 2 blocks/CU guaranteed.
__global__ __launch_bounds__(1024, 8) void k_coop(
        const float* __restrict__ pred, const float* __restrict__ tgt,
        const float* __restrict__ rnd,  const float* __restrict__ hard_rand,
        const float* __restrict__ pos_prop, Ws* __restrict__ ws,
        float* __restrict__ out)
{
    cg::grid_group grid = cg::this_grid();
    const int bid = blockIdx.x;
    const int c = bid >> 3, chunk = bid & 7;
    const int tid = threadIdx.x, lane = tid & 63, wv = tid >> 6;

    __shared__ union { unsigned h[4096]; double sd[1024]; } shu;
    __shared__ unsigned wsum[16];
    __shared__ unsigned out2[2];
    __shared__ double s_lns[CN];
    __shared__ int s_pos;
    __shared__ int s_active, s_kdrop;
    __shared__ unsigned s_majb;

    // -------- P0: params (block-local, redundant => no sync needed) --------
    for (int j = wv; j < CN; j += 16) {
        double s = 0.0;
        for (int q = lane; q < NBLK; q += 64)
            s += (double)ws->u.parts.lpart[j][q];
        #pragma unroll
        for (int d = 32; d >= 1; d >>= 1) s += __shfl_down(s, d, 64);
        if (lane == 0) s_lns[j] = log10(1.0 + s);
    }
    if (wv == 15) {
        int p = 0;
        for (int q = lane; q < NBLK; q += 64) p += ws->u.parts.ppart[c][q];
        #pragma unroll
        for (int d = 32; d >= 1; d >>= 1) p += __shfl_down(p, d, 64);
        if (lane == 0) s_pos = p;
    }
    __syncthreads();
    if (tid == 0) {
        double mn = s_lns[0], mx = s_lns[0];
        for (int i = 1; i < CN; ++i) { mn = fmin(mn, s_lns[i]); mx = fmax(mx, s_lns[i]); }
        double norm = 5.0 - 10.0 * (s_lns[c] - mn) / (mx - mn);
        float drate = (float)(1.0 / (1.0 + exp(-norm)));   // BASE_RATE = 0
        float Bf = (float)BN;
        float pos_sum = (float)s_pos;
        float neg_sum = Bf - pos_sum;
        float bal_pos = pos_prop[c] * Bf;
        float bal_neg = Bf - bal_pos;
        bool pos_gt = pos_sum > bal_pos;
        bool neg_gt = neg_sum > bal_neg;
        float balance = pos_gt ? bal_pos : (neg_gt ? bal_neg : 0.0f);
        float dnum_f  = pos_gt ? (pos_sum - bal_pos)
                               : (neg_gt ? (neg_sum - bal_neg) : 0.0f);
        int   kdrop   = (int)floorf(dnum_f);
        float majl = pos_gt ? 1.0f : 0.0f;
        float minl = neg_gt ? 1.0f : 0.0f;
        float maj_cnt = (majl == 1.0f) ? pos_sum : neg_sum;
        float min_cnt = (minl == 1.0f) ? pos_sum : neg_sum;
        int hardf = (hard_rand[c] > drate) ? 1 : 0;
        if (chunk == 0) {
            ws->drate[c]  = drate;
            ws->majl[c]   = majl;
            ws->minl[c]   = minl;
            ws->w_hard[c] = balance / fmaxf(maj_cnt, 1.0f);
            ws->w_easy[c] = (Bf - balance) / fmaxf(min_cnt, 1.0f);
            ws->hardf[c]  = hardf;
            ws->kdrop[c]  = kdrop;
            ws->minpos[c] = (min_cnt > 0.0f) ? 1 : 0;
        }
        s_active = (kdrop > 0 && hardf == 0) ? 1 : 0;
        s_kdrop  = kdrop;
        s_majb   = (majl != 0.0f) ? 1u : 0u;
    }
    __syncthreads();
    const bool active = (s_active != 0);
    const unsigned kdrop = (unsigned)s_kdrop;
    const unsigned majb = s_majb;
    const uint4* kc4 = (const uint4*)(ws->keys[c] + chunk * CROWS);

    // -------- hist0 (ghist pre-zeroed by memset) --------
    if (active) {
        for (int i = tid; i < 4096; i += 1024) shu.h[i] = 0;
        __syncthreads();
        for (int b4 = tid; b4 < CROWS / 4; b4 += 1024) {
            uint4 kk = kc4[b4];
            unsigned ks[4] = {kk.x, kk.y, kk.z, kk.w};
            #pragma unroll
            for (int q = 0; q < 4; ++q)
                if ((ks[q] & 1u) == majb) atomicAdd(&shu.h[(ks[q] >> 1) >> 18], 1u);
        }
        __syncthreads();
        for (int i = tid; i < 4096; i += 1024)
            if (shu.h[i]) atomicAdd(&ws->ghist0[c][i], shu.h[i]);
    }
    __threadfence();
    grid.sync();                                   // S1

    // -------- P1: pick0 + hist1 --------
    unsigned p0 = 0, krem1 = 0;
    if (active) {
        scan_pick<4, 4096>(ws->ghist0[c], kdrop, wsum, out2);
        p0 = out2[0]; krem1 = out2[1];
        shu.h[tid] = 0;
        __syncthreads();
        for (int b4 = tid; b4 < CROWS / 4; b4 += 1024) {
            uint4 kk = kc4[b4];
            unsigned ks[4] = {kk.x, kk.y, kk.z, kk.w};
            #pragma unroll
            for (int q = 0; q < 4; ++q)
                if ((ks[q] & 1u) == majb) {
                    unsigned mk = ks[q] >> 1;
                    if ((mk >> 18) == p0) atomicAdd(&shu.h[(mk >> 8) & 0x3FFu], 1u);
                }
        }
        __syncthreads();
        if (shu.h[tid]) atomicAdd(&ws->ghist1[c][tid], shu.h[tid]);
    }
    __threadfence();
    grid.sync();                                   // S2

    // -------- P2: pick1 + hist2 --------
    unsigned p01 = 0, krem2 = 0;
    if (active) {
        scan_pick<1, 1024>(ws->ghist1[c], krem1, wsum, out2);
        p01 = (p0 << 10) | out2[0]; krem2 = out2[1];
        if (tid < 256) shu.h[tid] = 0;
        __syncthreads();
        for (int b4 = tid; b4 < CROWS / 4; b4 += 1024) {
            uint4 kk = kc4[b4];
            unsigned ks[4] = {kk.x, kk.y, kk.z, kk.w};
            #pragma unroll
            for (int q = 0; q < 4; ++q)
                if ((ks[q] & 1u) == majb) {
                    unsigned mk = ks[q] >> 1;
                    if ((mk >> 8) == p01) atomicAdd(&shu.h[mk & 0xFFu], 1u);
                }
        }
        __syncthreads();
        if (tid < 256 && shu.h[tid]) atomicAdd(&ws->ghist2[c][tid], shu.h[tid]);
    }
    __threadfence();
    grid.sync();                                   // S3

    // -------- P3: pick2 -> T; mask ballot pass --------
    unsigned need = 0;
    unsigned long long* mrow = ws->u.mask[c];
    if (active) {
        scan_pick<1, 256>(ws->ghist2[c], krem2, wsum, out2);
        unsigned T = (p01 << 8) | out2[0];
        need = out2[1];
        const unsigned* kc = ws->keys[c];
        unsigned long long* erow = ws->eqmask[c];
        int base = chunk * CROWS;
        for (int it = 0; it < CROWS / 1024; ++it) {
            int b = base + it * 1024 + tid;
            unsigned m = masked_key(kc[b], majb);   // sentinel > T always
            unsigned long long blt = __ballot(m < T);
            unsigned long long beq = __ballot(m == T);
            if (lane == 0) {
                int word = (base >> 6) + it * 16 + wv;
                mrow[word] = blt;
                erow[word] = beq;
            }
        }
    } else {
        int w0 = chunk * (MASKW / NCHUNK);
        if (tid < MASKW / NCHUNK) mrow[w0 + tid] = 0ull;
    }
    __threadfence();
    grid.sync();                                   // S4

    // -------- P4: tie fixup (chunk==0 blocks) --------
    if (active && chunk == 0) {
        const unsigned long long* erow = ws->eqmask[c];
        unsigned long long e0 = erow[2 * tid], e1 = erow[2 * tid + 1];
        unsigned pc0 = (unsigned)__popcll(e0), pc1 = (unsigned)__popcll(e1);
        unsigned cnt = pc0 + pc1;
        unsigned isc = cnt;
        #pragma unroll
        for (int d = 1; d < 64; d <<= 1) {
            unsigned o = __shfl_up(isc, (unsigned)d, 64);
            if (lane >= d) isc += o;
        }
        if (lane == 63) wsum[wv] = isc;
        __syncthreads();
        unsigned wpre = 0;
        #pragma unroll
        for (int j = 0; j < 16; ++j) wpre += (j < wv) ? wsum[j] : 0u;
        unsigned prev = wpre + isc - cnt;
        #pragma unroll
        for (int half = 0; half < 2; ++half) {
            unsigned long long e = half ? e1 : e0;
            unsigned pc = half ? pc1 : pc0;
            unsigned p  = half ? prev + pc0 : prev;
            if (pc > 0 && p < need) {
                unsigned keep = need - p;
                if (keep > pc) keep = pc;
                unsigned long long sel;
                if (keep == pc) sel = e;
                else {
                    sel = 0ull;
                    unsigned long long m = e;
                    for (unsigned i = 0; i < keep; ++i) {
                        unsigned long long lsb = m & (~m + 1ull);
                        sel |= lsb;
                        m ^= lsb;
                    }
                }
                mrow[2 * tid + half] |= sel;
            }
        }
    }
    __threadfence();
    grid.sync();                                   // S5

    // -------- P5: final weighted sum --------
    {
        int gtid = bid * 1024 + tid;
        int c0 = (gtid * 4) % 40;      // stride 1310720 == 0 mod 40 -> fixed
        float drate4[4], majl4[4], minl4[4], wh4[4], we4[4];
        int hf4[4], mp4[4];
        #pragma unroll
        for (int u = 0; u < 4; ++u) {
            int cc = c0 + u;
            drate4[u] = ws->drate[cc]; majl4[u] = ws->majl[cc]; minl4[u] = ws->minl[cc];
            wh4[u] = ws->w_hard[cc];   we4[u] = ws->w_easy[cc];
            hf4[u] = ws->hardf[cc];    mp4[u] = ws->minpos[cc];
        }
        double acc = 0.0;
        #pragma unroll
        for (int it = 0; it < 4; ++it) {
            long i = (long)gtid * 4 + (long)it * (CN * NCHUNK * 1024L * 4);
            const float4 p  = *(const float4*)(pred + i);
            const float4 t  = *(const float4*)(tgt + i);
            const float4 rr = *(const float4*)(rnd + i);
            int b = (int)(i / 40);
            int wsh = b >> 6, bit = b & 63;
            #pragma unroll
            for (int u = 0; u < 4; ++u) {
                float pu = (&p.x)[u], tu = (&t.x)[u], ru = (&rr.x)[u];
                float bce, g;
                bce_g(pu, tu, bce, g);
                float wgt;
                if (hf4[u]) {
                    wgt = (tu == majl4[u]) ? wh4[u] : 1.0f;
                } else {
                    bool dropped = (ws->u.mask[c0 + u][wsh] >> bit) & 1ull;
                    wgt = dropped ? 0.0f : ((tu == minl4[u] && mp4[u]) ? we4[u] : 1.0f);
                }
                if (g >= 0.8f && g < 1.000001f && ru > drate4[u]) wgt = 0.0f;
                acc += (double)(bce * wgt);
            }
        }
        __syncthreads();
        shu.sd[tid] = acc;
        __syncthreads();
        for (int s = 512; s >= 1; s >>= 1) {
            if (tid < s) shu.sd[tid] += shu.sd[tid + s];
            __syncthreads();
        }
        if (tid == 0) atomicAdd(&ws->acc, shu.sd[0]);
    }
    __threadfence();
    grid.sync();                                   // S6
    if (bid == 0 && tid == 0) out[0] = (float)(ws->acc / (double)NTOT);
}

// ================================================================ NON-COOP
// fallback path (round-5 proven), used only if cooperative launch fails.
__global__ __launch_bounds__(1024) void k_params(const float* __restrict__ hard_rand,
                                                 const float* __restrict__ pos_prop,
                                                 Ws* __restrict__ ws, int use_part) {
    int tid = threadIdx.x;
    __shared__ double sred[CN][17];
    __shared__ int    spre[CN][17];
    __shared__ double lossv[CN];
    __shared__ int    posv[CN];
    __shared__ double lns[CN];
    __shared__ double smn, smx;
    if (use_part) {
        if (tid < CN * 16) {
            int c = tid >> 4, j = tid & 15;
            double s = 0.0; int p = 0;
            for (int i = j; i < NBLK; i += 16) {
                s += (double)ws->u.parts.lpart[c][i];
                p += ws->u.parts.ppart[c][i];
            }
            sred[c][j] = s; spre[c][j] = p;
        }
        __syncthreads();
        if (tid < CN) {
            double s = 0.0; int p = 0;
            for (int j = 0; j < 16; ++j) { s += sred[tid][j]; p += spre[tid][j]; }
            lossv[tid] = s; posv[tid] = p;
        }
    } else {
        if (tid < CN) { lossv[tid] = ws->lossc[tid]; posv[tid] = ws->posc[tid]; }
    }
    __syncthreads();
    if (tid < CN) lns[tid] = log10(1.0 + lossv[tid]);
    __syncthreads();
    if (tid == 0) {
        double a = lns[0], b = lns[0];
        for (int i = 1; i < CN; i++) { a = fmin(a, lns[i]); b = fmax(b, lns[i]); }
        smn = a; smx = b;
    }
    __syncthreads();
    if (tid < CN) {
        int c = tid;
        double norm = 5.0 - 10.0 * (lns[c] - smn) / (smx - smn);
        float drate = (float)(1.0 / (1.0 + exp(-norm)));
        float Bf = (float)BN;
        float pos_sum = (float)posv[c];
        float neg_sum = Bf - pos_sum;
        float bal_pos = pos_prop[c] * Bf;
        float bal_neg = Bf - bal_pos;
        bool pos_gt = pos_sum > bal_pos;
        bool neg_gt = neg_sum > bal_neg;
        float balance = pos_gt ? bal_pos : (neg_gt ? bal_neg : 0.0f);
        float dnum_f  = pos_gt ? (pos_sum - bal_pos)
                               : (neg_gt ? (neg_sum - bal_neg) : 0.0f);
        int   kdrop   = (int)floorf(dnum_f);
        float majl = pos_gt ? 1.0f : 0.0f;
        float minl = neg_gt ? 1.0f : 0.0f;
        float maj_cnt = (majl == 1.0f) ? pos_sum : neg_sum;
        float min_cnt = (minl == 1.0f) ? pos_sum : neg_sum;
        ws->drate[c]  = drate;
        ws->majl[c]   = majl;
        ws->minl[c]   = minl;
        ws->w_hard[c] = balance / fmaxf(maj_cnt, 1.0f);
        ws->w_easy[c] = (Bf - balance) / fmaxf(min_cnt, 1.0f);
        ws->hardf[c]  = (hard_rand[c] > drate) ? 1 : 0;
        ws->kdrop[c]  = kdrop;
        ws->minpos[c] = (min_cnt > 0.0f) ? 1 : 0;
    }
}

__global__ __launch_bounds__(1024) void k_hist0(Ws* __restrict__ ws) {
    int c = blockIdx.x >> 3, chunk = blockIdx.x & 7;
    if (!col_active(ws, c)) return;
    unsigned majb = (ws->majl[c] != 0.0f) ? 1u : 0u;
    const uint4* __restrict__ kc4 = (const uint4*)(ws->keys[c] + chunk * CROWS);
    __shared__ unsigned h[4096];
    int tid = threadIdx.x;
    for (int i = tid; i < 4096; i += 1024) h[i] = 0;
    __syncthreads();
    for (int b4 = tid; b4 < CROWS / 4; b4 += 1024) {
        uint4 kk = kc4[b4];
        unsigned ks[4] = {kk.x, kk.y, kk.z, kk.w};
        #pragma unroll
        for (int q = 0; q < 4; ++q)
            if ((ks[q] & 1u) == majb) atomicAdd(&h[(ks[q] >> 1) >> 18], 1u);
    }
    __syncthreads();
    for (int i = tid; i < 4096; i += 1024)
        if (h[i]) atomicAdd(&ws->ghist0[c][i], h[i]);
}

__global__ __launch_bounds__(1024) void k_hist1(Ws* __restrict__ ws) {
    int c = blockIdx.x >> 3, chunk = blockIdx.x & 7;
    if (!col_active(ws, c)) return;
    __shared__ unsigned wsum[16];
    __shared__ unsigned out2[2];
    scan_pick<4, 4096>(ws->ghist0[c], (unsigned)ws->kdrop[c], wsum, out2);
    unsigned p0 = out2[0];
    unsigned majb = (ws->majl[c] != 0.0f) ? 1u : 0u;
    const uint4* __restrict__ kc4 = (const uint4*)(ws->keys[c] + chunk * CROWS);
    __shared__ unsigned h[1024];
    int tid = threadIdx.x;
    h[tid] = 0;
    __syncthreads();
    for (int b4 = tid; b4 < CROWS / 4; b4 += 1024) {
        uint4 kk = kc4[b4];
        unsigned ks[4] = {kk.x, kk.y, kk.z, kk.w};
        #pragma unroll
        for (int q = 0; q < 4; ++q)
            if ((ks[q] & 1u) == majb) {
                unsigned mk = ks[q] >> 1;
                if ((mk >> 18) == p0) atomicAdd(&h[(mk >> 8) & 0x3FFu], 1u);
            }
    }
    __syncthreads();
    if (h[tid]) atomicAdd(&ws->ghist1[c][tid], h[tid]);
}

__global__ __launch_bounds__(1024) void k_hist2(Ws* __restrict__ ws) {
    int c = blockIdx.x >> 3, chunk = blockIdx.x & 7;
    if (!col_active(ws, c)) return;
    __shared__ unsigned wsum[16];
    __shared__ unsigned out2[2];
    scan_pick<4, 4096>(ws->ghist0[c], (unsigned)ws->kdrop[c], wsum, out2);
    unsigned p0 = out2[0], krem1 = out2[1];
    scan_pick<1, 1024>(ws->ghist1[c], krem1, wsum, out2);
    unsigned pp = (p0 << 10) | out2[0];
    unsigned majb = (ws->majl[c] != 0.0f) ? 1u : 0u;
    const uint4* __restrict__ kc4 = (const uint4*)(ws->keys[c] + chunk * CROWS);
    __shared__ unsigned h[256];
    int tid = threadIdx.x;
    if (tid < 256) h[tid] = 0;
    __syncthreads();
    for (int b4 = tid; b4 < CROWS / 4; b4 += 1024) {
        uint4 kk = kc4[b4];
        unsigned ks[4] = {kk.x, kk.y, kk.z, kk.w};
        #pragma unroll
        for (int q = 0; q < 4; ++q)
            if ((ks[q] & 1u) == majb) {
                unsigned mk = ks[q] >> 1;
                if ((mk >> 8) == pp) atomicAdd(&h[mk & 0xFFu], 1u);
            }
    }
    __syncthreads();
    if (tid < 256 && h[tid]) atomicAdd(&ws->ghist2[c][tid], h[tid]);
}

__global__ __launch_bounds__(1024) void k_mask(Ws* __restrict__ ws) {
    int c = blockIdx.x >> 3, chunk = blockIdx.x & 7;
    int tid = threadIdx.x;
    unsigned long long* mrow = ws->u.mask[c];
    if (!col_active(ws, c)) {
        if (tid < MASKW / NCHUNK) mrow[chunk * (MASKW / NCHUNK) + tid] = 0ull;
        return;
    }
    __shared__ unsigned wsum[16];
    __shared__ unsigned out2[2];
    scan_pick<4, 4096>(ws->ghist0[c], (unsigned)ws->kdrop[c], wsum, out2);
    unsigned p0 = out2[0], krem1 = out2[1];
    scan_pick<1, 1024>(ws->ghist1[c], krem1, wsum, out2);
    unsigned p1 = out2[0], krem2 = out2[1];
    scan_pick<1, 256>(ws->ghist2[c], krem2, wsum, out2);
    unsigned T = (p0 << 18) | (p1 << 8) | out2[0];

    unsigned majb = (ws->majl[c] != 0.0f) ? 1u : 0u;
    const unsigned* __restrict__ kc = ws->keys[c];
    unsigned long long* erow = ws->eqmask[c];
    int lane = tid & 63, w = tid >> 6;
    int base = chunk * CROWS;
    for (int it = 0; it < CROWS / 1024; ++it) {
        int b = base + it * 1024 + tid;
        unsigned m = masked_key(kc[b], majb);
        unsigned long long blt = __ballot(m < T);
        unsigned long long beq = __ballot(m == T);
        if (lane == 0) {
            int word = (base >> 6) + it * 16 + w;
            mrow[word] = blt;
            erow[word] = beq;
        }
    }
}

__global__ __launch_bounds__(1024) void k_tie(Ws* __restrict__ ws) {
    int c = blockIdx.x;
    if (!col_active(ws, c)) return;
    __shared__ unsigned wsum[16];
    __shared__ unsigned out2[2];
    scan_pick<4, 4096>(ws->ghist0[c], (unsigned)ws->kdrop[c], wsum, out2);
    unsigned krem1 = out2[1];
    scan_pick<1, 1024>(ws->ghist1[c], krem1, wsum, out2);
    unsigned krem2 = out2[1];
    scan_pick<1, 256>(ws->ghist2[c], krem2, wsum, out2);
    unsigned need = out2[1];

    int tid = threadIdx.x, lane = tid & 63, w = tid >> 6;
    const unsigned long long* erow = ws->eqmask[c];
    unsigned long long* mrow = ws->u.mask[c];
    unsigned long long e0 = erow[2 * tid], e1 = erow[2 * tid + 1];
    unsigned pc0 = (unsigned)__popcll(e0), pc1 = (unsigned)__popcll(e1);
    unsigned cnt = pc0 + pc1;
    unsigned isc = cnt;
    #pragma unroll
    for (int d = 1; d < 64; d <<= 1) {
        unsigned o = __shfl_up(isc, (unsigned)d, 64);
        if (lane >= d) isc += o;
    }
    if (lane == 63) wsum[w] = isc;
    __syncthreads();
    unsigned wpre = 0;
    #pragma unroll
    for (int j = 0; j < 16; ++j) wpre += (j < w) ? wsum[j] : 0u;
    unsigned prev = wpre + isc - cnt;
    #pragma unroll
    for (int half = 0; half < 2; ++half) {
        unsigned long long e = half ? e1 : e0;
        unsigned pc = half ? pc1 : pc0;
        unsigned p  = half ? prev + pc0 : prev;
        if (pc > 0 && p < need) {
            unsigned keep = need - p;
            if (keep > pc) keep = pc;
            unsigned long long sel;
            if (keep == pc) sel = e;
            else {
                sel = 0ull;
                unsigned long long m = e;
                for (unsigned i = 0; i < keep; ++i) {
                    unsigned long long lsb = m & (~m + 1ull);
                    sel |= lsb;
                    m ^= lsb;
                }
            }
            mrow[2 * tid + half] |= sel;
        }
    }
}

__global__ __launch_bounds__(640) void k_final2(const float* __restrict__ pred,
                                                const float* __restrict__ tgt,
                                                const float* __restrict__ rnd,
                                                Ws* __restrict__ ws) {
    int tid = threadIdx.x;
    long tile0 = (long)blockIdx.x * 5120;
    int  c0    = (tid * 4) % 40;
    float drate[4], majl[4], minl[4], wh[4], we[4];
    int hf[4], mp[4];
    #pragma unroll
    for (int u = 0; u < 4; ++u) {
        int c = c0 + u;
        drate[u] = ws->drate[c]; majl[u] = ws->majl[c]; minl[u] = ws->minl[c];
        wh[u] = ws->w_hard[c];   we[u] = ws->w_easy[c];
        hf[u] = ws->hardf[c];    mp[u] = ws->minpos[c];
    }
    double acc = 0.0;
    #pragma unroll
    for (int j = 0; j < 2; ++j) {
        long i = tile0 + j * 2560 + tid * 4;
        const float4 p  = *(const float4*)(pred + i);
        const float4 t  = *(const float4*)(tgt + i);
        const float4 rr = *(const float4*)(rnd + i);
        int b = (int)(i / 40);
        int wsh = b >> 6, bit = b & 63;
        #pragma unroll
        for (int u = 0; u < 4; ++u) {
            float pu = (&p.x)[u], tu = (&t.x)[u], ru = (&rr.x)[u];
            float bce, g;
            bce_g(pu, tu, bce, g);
            float w;
            if (hf[u]) {
                w = (tu == majl[u]) ? wh[u] : 1.0f;
            } else {
                bool dropped = (ws->u.mask[c0 + u][wsh] >> bit) & 1ull;
                w = dropped ? 0.0f : ((tu == minl[u] && mp[u]) ? we[u] : 1.0f);
            }
            if (g >= 0.8f && g < 1.000001f && ru > drate[u]) w = 0.0f;
            acc += (double)(bce * w);
        }
    }
    __shared__ double sd[640];
    sd[tid] = acc;
    __syncthreads();
    for (int s = 320; s >= 5; s >>= 1) {
        if (tid < s) sd[tid] += sd[tid + s];
        __syncthreads();
    }
    if (tid == 0) {
        double v = sd[0] + sd[1] + sd[2] + sd[3] + sd[4];
        atomicAdd(&ws->acc, v);
    }
}

__global__ void k_write(Ws* __restrict__ ws, float* __restrict__ out) {
    out[0] = (float)(ws->acc / (double)NTOT);
}

// ================================================================ round-1
// fallback (ws too small)
__global__ void k_colreduce(const float* __restrict__ pred,
                            const float* __restrict__ tgt,
                            Ws* __restrict__ ws) {
    __shared__ float sl[CN];
    __shared__ int   sp[CN];
    int tid = threadIdx.x;
    if (tid < CN) { sl[tid] = 0.0f; sp[tid] = 0; }
    __syncthreads();
    int stride = gridDim.x * blockDim.x;
    for (int i = blockIdx.x * blockDim.x + tid; i < NTOT; i += stride) {
        int c = i % CN;
        float p = pred[i], t = tgt[i];
        atomicAdd(&sl[c], bce_f(p, t));
        if (t != 0.0f) atomicAdd(&sp[c], 1);
    }
    __syncthreads();
    if (tid < CN) {
        atomicAdd(&ws->lossc[tid], (double)sl[tid]);
        atomicAdd(&ws->posc[tid], sp[tid]);
    }
}

__global__ __launch_bounds__(1024) void k_select(const float* __restrict__ pred,
                                                 const float* __restrict__ tgt,
                                                 Ws* __restrict__ ws) {
    int c   = blockIdx.x;
    int tid = threadIdx.x;
    int k   = ws->kdrop[c];
    bool easy = (ws->hardf[c] == 0);
    unsigned long long* mrow = ws->u.mask[c];
    if (k <= 0 || !easy) {
        for (int i = tid; i < MASKW; i += 1024) mrow[i] = 0ull;
        return;
    }
    float majl = ws->majl[c];
    __shared__ unsigned h[256];
    __shared__ unsigned cum[256];
    __shared__ unsigned sh_sel, sh_krem;
    unsigned prefix = 0;
    unsigned krem   = (unsigned)k;
    for (int level = 0; level < 4; ++level) {
        int shift = 24 - 8 * level;
        for (int i = tid; i < 256; i += 1024) h[i] = 0;
        __syncthreads();
        for (int b = tid; b < BN; b += 1024) {
            float t = tgt[b * CN + c];
            if (t == majl) {
                unsigned bits = __float_as_uint(g_f(pred[b * CN + c], t));
                bool ok = (level == 0) || ((bits >> (shift + 8)) == prefix);
                if (ok) atomicAdd(&h[(bits >> shift) & 0xFFu], 1u);
            }
        }
        __syncthreads();
        if (tid < 256) cum[tid] = h[tid];
        __syncthreads();
        for (int off = 1; off < 256; off <<= 1) {
            unsigned v = 0;
            if (tid < 256 && tid >= off) v = cum[tid - off];
            __syncthreads();
            if (tid < 256 && tid >= off) cum[tid] += v;
            __syncthreads();
        }
        if (tid < 256) {
            unsigned prev = (tid == 0) ? 0u : cum[tid - 1];
            if (cum[tid] >= krem && prev < krem) {
                sh_sel  = (unsigned)tid;
                sh_krem = krem - prev;
            }
        }
        __syncthreads();
        prefix = (prefix << 8) | sh_sel;
        krem   = sh_krem;
        __syncthreads();
    }
    unsigned T    = prefix;
    unsigned need = krem;
    __shared__ unsigned wcnt[16];
    unsigned base = 0;
    int lane = tid & 63, wid = tid >> 6;
    for (int chunk = 0; chunk < BN / 1024; ++chunk) {
        int b = chunk * 1024 + tid;
        float t = tgt[b * CN + c];
        bool ismaj = (t == majl);
        unsigned bits = 0xFFFFFFFFu;
        if (ismaj) bits = __float_as_uint(g_f(pred[b * CN + c], t));
        bool lt = ismaj && (bits < T);
        bool eq = ismaj && (bits == T);
        unsigned long long bal = __ballot(eq);
        if (lane == 0) wcnt[wid] = (unsigned)__popcll(bal);
        __syncthreads();
        unsigned woff = 0, tot = 0;
        for (int w = 0; w < 16; ++w) {
            unsigned v = wcnt[w];
            if (w < wid) woff += v;
            tot += v;
        }
        unsigned long long lanemask = (lane == 0) ? 0ull : ((~0ull) >> (64 - lane));
        unsigned myrank = base + woff + (unsigned)__popcll(bal & lanemask);
        bool dropped = lt || (eq && myrank < need);
        unsigned long long bd = __ballot(dropped);
        if (lane == 0) mrow[chunk * 16 + wid] = bd;
        base += tot;
        __syncthreads();
    }
}

__global__ void k_final(const float* __restrict__ pred,
                        const float* __restrict__ tgt,
                        const float* __restrict__ rnd,
                        Ws* __restrict__ ws) {
    __shared__ double sdata[256];
    double acc = 0.0;
    int stride = gridDim.x * blockDim.x;
    for (int i = blockIdx.x * blockDim.x + threadIdx.x; i < NTOT; i += stride) {
        int b = i / CN;
        int c = i - b * CN;
        float p = pred[i], t = tgt[i], r = rnd[i];
        float bce = bce_f(p, t);
        float g   = g_f(p, t);
        float w;
        if (ws->hardf[c]) {
            w = (t == ws->majl[c]) ? ws->w_hard[c] : 1.0f;
        } else {
            bool dropped = (ws->u.mask[c][b >> 6] >> (b & 63)) & 1ull;
            if (dropped) w = 0.0f;
            else w = ((t == ws->minl[c]) && ws->minpos[c]) ? ws->w_easy[c] : 1.0f;
        }
        if ((g >= 0.8f) && (g < 1.000001f) && (r > ws->drate[c])) w = 0.0f;
        acc += (double)(bce * w);
    }
    sdata[threadIdx.x] = acc;
    __syncthreads();
    for (int s = blockDim.x / 2; s > 0; s >>= 1) {
        if (threadIdx.x < s) sdata[threadIdx.x] += sdata[threadIdx.x + s];
        __syncthreads();
    }
    if (threadIdx.x == 0) atomicAdd(&ws->acc, sdata[0]);
}

extern "C" void kernel_launch(void* const* d_in, const int* in_sizes, int n_in,
                              void* d_out, int out_size, void* d_ws, size_t ws_size,
                              hipStream_t stream) {
    const float* pred      = (const float*)d_in[0];
    const float* tgt       = (const float*)d_in[1];
    const float* rnd       = (const float*)d_in[2];
    const float* hard_rand = (const float*)d_in[3];
    const float* pos_prop  = (const float*)d_in[4];
    Ws* ws = (Ws*)d_ws;

    if (ws_size >= sizeof(Ws)) {
        hipMemsetAsync(d_ws, 0, offsetof(Ws, lossc), stream);   // acc + ghists
        k_fuse<<<NBLK, 640, 0, stream>>>(pred, tgt, ws);
        float* outp = (float*)d_out;
        void* args[] = {(void*)&pred, (void*)&tgt, (void*)&rnd, (void*)&hard_rand,
                        (void*)&pos_prop, (void*)&ws, (void*)&outp};
        hipError_t err = hipLaunchCooperativeKernel((const void*)k_coop,
                             dim3(CN * NCHUNK), dim3(1024), args, 0, stream);
        if (err != hipSuccess) {
            // non-cooperative fallback (round-5 proven path)
            k_params<<<1, 1024, 0, stream>>>(hard_rand, pos_prop, ws, 1);
            k_hist0 <<<CN * NCHUNK, 1024, 0, stream>>>(ws);
            k_hist1 <<<CN * NCHUNK, 1024, 0, stream>>>(ws);
            k_hist2 <<<CN * NCHUNK, 1024, 0, stream>>>(ws);
            k_mask  <<<CN * NCHUNK, 1024, 0, stream>>>(ws);
            k_tie   <<<CN, 1024, 0, stream>>>(ws);
            k_final2<<<NBLK, 640, 0, stream>>>(pred, tgt, rnd, ws);
            k_write <<<1, 1, 0, stream>>>(ws, (float*)d_out);
        }
    } else {
        hipMemsetAsync(d_ws, 0, offsetof(Ws, drate), stream);
        k_colreduce<<<2048, 256, 0, stream>>>(pred, tgt, ws);
        k_params<<<1, 1024, 0, stream>>>(hard_rand, pos_prop, ws, 0);
        k_select<<<CN, 1024, 0, stream>>>(pred, tgt, ws);
        k_final <<<2048, 256, 0, stream>>>(pred, tgt, rnd, ws);
        k_write <<<1, 1, 0, stream>>>(ws, (float*)d_out);
    }
}

// Round 7
// 201.974 us; speedup vs baseline: 4.9390x; 4.9390x over previous
//
#include <hip/hip_runtime.h>
#include <hip/hip_bf16.h>
#include <math.h>
#include <stddef.h>

#define BN 131072
#define CN 40
#define NTOT (BN * CN)
#define MASKW (BN / 64)   // 2048 uint64 words per column
#define NBLK 1024         // k_fuse / k_final3 grid
#define NCHUNK 8          // selection chunks per column
#define CROWS (BN / NCHUNK)   // 16384 rows per chunk

// Workspace layout. Zeroed region = [acc .. ghist2] (one memset).
// u.mask is union'd with k_fuse partials: fuse writes parts -> sel0 reads
// -> k_mask overwrites mask.
struct Ws {
    double acc;
    unsigned done;
    unsigned pad0;
    unsigned ghist0[CN][4096];         // level-0 hist (digit = mk>>18, <=4064)
    unsigned ghist1[CN][1024];         // level-1 hist (digit = (mk>>8)&0x3FF)
    unsigned ghist2[CN][256];          // level-2 hist (digit = mk&0xFF)
    // ---- not zeroed below (fast path) ----
    double lossc[CN];                  // round-1 fallback only
    int    posc[CN];                   // round-1 fallback only
    float drate[CN];
    float majl[CN];
    float minl[CN];
    float w_hard[CN];
    float w_easy[CN];
    int   hardf[CN];
    int   kdrop[CN];
    int   minpos[CN];
    union {
        unsigned long long mask[CN][MASKW];                           // 640 KB
        struct { float lpart[CN][NBLK]; int ppart[CN][NBLK]; } parts; // 320 KB
    } u;
    unsigned long long eqmask[CN][MASKW];  // ==T ballot masks (640 KB)
    unsigned keys[CN][BN];                 // transposed packed (g_bits<<1)|t
};

__device__ __forceinline__ float bce_f(float x, float t) {
    float e = __expf(-fabsf(x));
    return fmaxf(x, 0.0f) + __logf(1.0f + e) - x * t;
}
__device__ __forceinline__ float g_f(float x, float t) {
    float e   = __expf(-fabsf(x));
    float inv = __builtin_amdgcn_rcpf(1.0f + e);
    float s   = (x >= 0.0f) ? inv : e * inv;
    return fabsf(s - t);
}
// fused fast version: one exp for both bce and g
__device__ __forceinline__ void bce_g(float x, float t, float& bce, float& g) {
    float e   = __expf(-fabsf(x));
    bce       = fmaxf(x, 0.0f) + __logf(1.0f + e) - x * t;
    float inv = __builtin_amdgcn_rcpf(1.0f + e);
    float s   = (x >= 0.0f) ? inv : e * inv;   // stable sigmoid
    g         = fabsf(s - t);
}
__device__ __forceinline__ unsigned masked_key(unsigned key, unsigned majb) {
    return ((key & 1u) == majb) ? (key >> 1) : 0xFFFFFFFFu;
}
__device__ __forceinline__ bool col_active(const Ws* ws, int c) {
    return (ws->kdrop[c] > 0) && (ws->hardf[c] == 0);
}

// Block-wide pick: first bin where cumulative count >= krem.
// 1024 threads, PER bins/thread. out2[0]=bin, out2[1]=krem-prefix(bin).
template<int PER, int NBINS>
__device__ __forceinline__ void scan_pick(const unsigned* __restrict__ gh,
                                          unsigned krem,
                                          unsigned* wsum /*[16]*/,
                                          unsigned* out2 /*[2]*/) {
    int tid = threadIdx.x, lane = tid & 63, w = tid >> 6;
    unsigned v[PER];
    unsigned s = 0;
    #pragma unroll
    for (int i = 0; i < PER; ++i) {
        int idx = tid * PER + i;
        v[i] = (idx < NBINS) ? gh[idx] : 0u;
        s += v[i];
    }
    unsigned isc = s;
    #pragma unroll
    for (int d = 1; d < 64; d <<= 1) {
        unsigned o = __shfl_up(isc, (unsigned)d, 64);
        if (lane >= d) isc += o;
    }
    if (lane == 63) wsum[w] = isc;
    __syncthreads();
    unsigned wpre = 0;
    #pragma unroll
    for (int j = 0; j < 16; ++j) wpre += (j < w) ? wsum[j] : 0u;
    unsigned inc = wpre + isc, prev = inc - s;
    if (prev < krem && inc >= krem) {
        unsigned cum = prev;
        #pragma unroll
        for (int i = 0; i < PER; ++i) {
            if (cum < krem && cum + v[i] >= krem) {
                out2[0] = (unsigned)(tid * PER + i);
                out2[1] = krem - cum;
            }
            cum += v[i];
        }
    }
    __syncthreads();
}

// ================================================================ kernel A
// Fused: per-column bce sum + pos count + LDS-tiled transpose of packed keys.
// XCD-swizzled tile mapping for L2-local selection reads.
__global__ __launch_bounds__(640) void k_fuse(const float* __restrict__ pred,
                                              const float* __restrict__ tgt,
                                              Ws* __restrict__ ws) {
    __shared__ unsigned shk[128 * 41];   // +1 pad kills stride-40 bank conflict
    __shared__ float sl[CN];
    __shared__ int   sp[CN];
    int tid = threadIdx.x;
    if (tid < CN) { sl[tid] = 0.0f; sp[tid] = 0; }
    __syncthreads();

    int  tile  = (blockIdx.x & 7) * 128 + (blockIdx.x >> 3);   // XCD swizzle
    long tile0 = (long)tile * 5120;
    int  c0    = (tid * 4) % 40;         // fixed 4 columns per thread
    float accl[4] = {0, 0, 0, 0};
    int   cntp[4] = {0, 0, 0, 0};

    #pragma unroll
    for (int j = 0; j < 2; ++j) {
        int e = j * 2560 + tid * 4;
        const float4 p = *(const float4*)(pred + tile0 + e);
        const float4 t = *(const float4*)(tgt + tile0 + e);
        int r = e / 40;
        #pragma unroll
        for (int u = 0; u < 4; ++u) {
            float pu = (&p.x)[u], tu = (&t.x)[u];
            float bce, g;
            bce_g(pu, tu, bce, g);
            accl[u] += bce;
            int tb = (tu != 0.0f) ? 1 : 0;
            cntp[u] += tb;
            shk[r * 41 + c0 + u] = (__float_as_uint(g) << 1) | (unsigned)tb;
        }
    }
    #pragma unroll
    for (int u = 0; u < 4; ++u) {
        atomicAdd(&sl[c0 + u], accl[u]);
        atomicAdd(&sp[c0 + u], cntp[u]);
    }
    __syncthreads();

    int w = tid / 128, r = tid % 128;
    int row0 = tile * 128;
    #pragma unroll
    for (int cc = 0; cc < 8; ++cc) {
        int c = w * 8 + cc;
        ws->keys[c][row0 + r] = shk[r * 41 + c];
    }
    if (tid < CN) {
        ws->u.parts.lpart[tid][blockIdx.x] = sl[tid];
        ws->u.parts.ppart[tid][blockIdx.x] = sp[tid];
    }
}

// ================================================================ kernel SEL0
// grid = CN*NCHUNK. Each block redundantly computes params from the k_fuse
// partials (deterministic => all blocks agree); chunk-0 blocks publish them.
// Then LDS 4096-bin hist of mk>>18, flushed with one global atomic per bin.
__global__ __launch_bounds__(1024) void k_sel0(const float* __restrict__ hard_rand,
                                               const float* __restrict__ pos_prop,
                                               Ws* __restrict__ ws) {
    const int bid = blockIdx.x;
    const int c = bid >> 3, chunk = bid & 7;
    const int tid = threadIdx.x, lane = tid & 63, wv = tid >> 6;

    __shared__ unsigned h[4096];
    __shared__ double s_lns[CN];
    __shared__ int s_pos;
    __shared__ int s_active, s_kdrop;
    __shared__ unsigned s_majb;

    // -------- params (block-local, redundant) --------
    for (int j = wv; j < CN; j += 16) {
        double s = 0.0;
        for (int q = lane; q < NBLK; q += 64)
            s += (double)ws->u.parts.lpart[j][q];
        #pragma unroll
        for (int d = 32; d >= 1; d >>= 1) s += __shfl_down(s, d, 64);
        if (lane == 0) s_lns[j] = log10(1.0 + s);
    }
    if (wv == 15) {
        int p = 0;
        for (int q = lane; q < NBLK; q += 64) p += ws->u.parts.ppart[c][q];
        #pragma unroll
        for (int d = 32; d >= 1; d >>= 1) p += __shfl_down(p, d, 64);
        if (lane == 0) s_pos = p;
    }
    __syncthreads();
    if (tid == 0) {
        double mn = s_lns[0], mx = s_lns[0];
        for (int i = 1; i < CN; ++i) { mn = fmin(mn, s_lns[i]); mx = fmax(mx, s_lns[i]); }
        double norm = 5.0 - 10.0 * (s_lns[c] - mn) / (mx - mn);
        float drate = (float)(1.0 / (1.0 + exp(-norm)));   // BASE_RATE = 0
        float Bf = (float)BN;
        float pos_sum = (float)s_pos;
        float neg_sum = Bf - pos_sum;
        float bal_pos = pos_prop[c] * Bf;
        float bal_neg = Bf - bal_pos;
        bool pos_gt = pos_sum > bal_pos;
        bool neg_gt = neg_sum > bal_neg;
        float balance = pos_gt ? bal_pos : (neg_gt ? bal_neg : 0.0f);
        float dnum_f  = pos_gt ? (pos_sum - bal_pos)
                               : (neg_gt ? (neg_sum - bal_neg) : 0.0f);
        int   kdrop   = (int)floorf(dnum_f);
        float majl = pos_gt ? 1.0f : 0.0f;
        float minl = neg_gt ? 1.0f : 0.0f;
        float maj_cnt = (majl == 1.0f) ? pos_sum : neg_sum;
        float min_cnt = (minl == 1.0f) ? pos_sum : neg_sum;
        int hardf = (hard_rand[c] > drate) ? 1 : 0;
        if (chunk == 0) {
            ws->drate[c]  = drate;
            ws->majl[c]   = majl;
            ws->minl[c]   = minl;
            ws->w_hard[c] = balance / fmaxf(maj_cnt, 1.0f);
            ws->w_easy[c] = (Bf - balance) / fmaxf(min_cnt, 1.0f);
            ws->hardf[c]  = hardf;
            ws->kdrop[c]  = kdrop;
            ws->minpos[c] = (min_cnt > 0.0f) ? 1 : 0;
        }
        s_active = (kdrop > 0 && hardf == 0) ? 1 : 0;
        s_kdrop  = kdrop;
        s_majb   = (majl != 0.0f) ? 1u : 0u;
    }
    __syncthreads();
    if (!s_active) return;
    const unsigned majb = s_majb;
    const uint4* kc4 = (const uint4*)(ws->keys[c] + chunk * CROWS);

    // -------- hist0 (ghist pre-zeroed by memset) --------
    for (int i = tid; i < 4096; i += 1024) h[i] = 0;
    __syncthreads();
    for (int b4 = tid; b4 < CROWS / 4; b4 += 1024) {
        uint4 kk = kc4[b4];
        unsigned ks[4] = {kk.x, kk.y, kk.z, kk.w};
        #pragma unroll
        for (int q = 0; q < 4; ++q)
            if ((ks[q] & 1u) == majb) atomicAdd(&h[(ks[q] >> 1) >> 18], 1u);
    }
    __syncthreads();
    for (int i = tid; i < 4096; i += 1024)
        if (h[i]) atomicAdd(&ws->ghist0[c][i], h[i]);
}

// ================================================================ kernel H1
__global__ __launch_bounds__(1024) void k_hist1(Ws* __restrict__ ws) {
    int c = blockIdx.x >> 3, chunk = blockIdx.x & 7;
    if (!col_active(ws, c)) return;
    __shared__ unsigned wsum[16];
    __shared__ unsigned out2[2];
    scan_pick<4, 4096>(ws->ghist0[c], (unsigned)ws->kdrop[c], wsum, out2);
    unsigned p0 = out2[0];
    unsigned majb = (ws->majl[c] != 0.0f) ? 1u : 0u;
    const uint4* __restrict__ kc4 = (const uint4*)(ws->keys[c] + chunk * CROWS);
    __shared__ unsigned h[1024];
    int tid = threadIdx.x;
    h[tid] = 0;
    __syncthreads();
    for (int b4 = tid; b4 < CROWS / 4; b4 += 1024) {
        uint4 kk = kc4[b4];
        unsigned ks[4] = {kk.x, kk.y, kk.z, kk.w};
        #pragma unroll
        for (int q = 0; q < 4; ++q)
            if ((ks[q] & 1u) == majb) {
                unsigned mk = ks[q] >> 1;
                if ((mk >> 18) == p0) atomicAdd(&h[(mk >> 8) & 0x3FFu], 1u);
            }
    }
    __syncthreads();
    if (h[tid]) atomicAdd(&ws->ghist1[c][tid], h[tid]);
}

// ================================================================ kernel H2
__global__ __launch_bounds__(1024) void k_hist2(Ws* __restrict__ ws) {
    int c = blockIdx.x >> 3, chunk = blockIdx.x & 7;
    if (!col_active(ws, c)) return;
    __shared__ unsigned wsum[16];
    __shared__ unsigned out2[2];
    scan_pick<4, 4096>(ws->ghist0[c], (unsigned)ws->kdrop[c], wsum, out2);
    unsigned p0 = out2[0], krem1 = out2[1];
    scan_pick<1, 1024>(ws->ghist1[c], krem1, wsum, out2);
    unsigned pp = (p0 << 10) | out2[0];
    unsigned majb = (ws->majl[c] != 0.0f) ? 1u : 0u;
    const uint4* __restrict__ kc4 = (const uint4*)(ws->keys[c] + chunk * CROWS);
    __shared__ unsigned h[256];
    int tid = threadIdx.x;
    if (tid < 256) h[tid] = 0;
    __syncthreads();
    for (int b4 = tid; b4 < CROWS / 4; b4 += 1024) {
        uint4 kk = kc4[b4];
        unsigned ks[4] = {kk.x, kk.y, kk.z, kk.w};
        #pragma unroll
        for (int q = 0; q < 4; ++q)
            if ((ks[q] & 1u) == majb) {
                unsigned mk = ks[q] >> 1;
                if ((mk >> 8) == pp) atomicAdd(&h[mk & 0xFFu], 1u);
            }
    }
    __syncthreads();
    if (tid < 256 && h[tid]) atomicAdd(&ws->ghist2[c][tid], h[tid]);
}

// ================================================================ kernel M
__global__ __launch_bounds__(1024) void k_mask(Ws* __restrict__ ws) {
    int c = blockIdx.x >> 3, chunk = blockIdx.x & 7;
    int tid = threadIdx.x;
    unsigned long long* mrow = ws->u.mask[c];
    if (!col_active(ws, c)) {
        if (tid < MASKW / NCHUNK) mrow[chunk * (MASKW / NCHUNK) + tid] = 0ull;
        return;
    }
    __shared__ unsigned wsum[16];
    __shared__ unsigned out2[2];
    scan_pick<4, 4096>(ws->ghist0[c], (unsigned)ws->kdrop[c], wsum, out2);
    unsigned p0 = out2[0], krem1 = out2[1];
    scan_pick<1, 1024>(ws->ghist1[c], krem1, wsum, out2);
    unsigned p1 = out2[0], krem2 = out2[1];
    scan_pick<1, 256>(ws->ghist2[c], krem2, wsum, out2);
    unsigned T = (p0 << 18) | (p1 << 8) | out2[0];

    unsigned majb = (ws->majl[c] != 0.0f) ? 1u : 0u;
    const unsigned* __restrict__ kc = ws->keys[c];
    unsigned long long* erow = ws->eqmask[c];
    int lane = tid & 63, w = tid >> 6;
    int base = chunk * CROWS;
    for (int it = 0; it < CROWS / 1024; ++it) {
        int b = base + it * 1024 + tid;
        unsigned m = masked_key(kc[b], majb);   // sentinel > T always
        unsigned long long blt = __ballot(m < T);
        unsigned long long beq = __ballot(m == T);
        if (lane == 0) {
            int word = (base >> 6) + it * 16 + w;
            mrow[word] = blt;
            erow[word] = beq;
        }
    }
}

// ================================================================ kernel Tie
__global__ __launch_bounds__(1024) void k_tie(Ws* __restrict__ ws) {
    int c = blockIdx.x;
    if (!col_active(ws, c)) return;
    __shared__ unsigned wsum[16];
    __shared__ unsigned out2[2];
    scan_pick<4, 4096>(ws->ghist0[c], (unsigned)ws->kdrop[c], wsum, out2);
    unsigned krem1 = out2[1];
    scan_pick<1, 1024>(ws->ghist1[c], krem1, wsum, out2);
    unsigned krem2 = out2[1];
    scan_pick<1, 256>(ws->ghist2[c], krem2, wsum, out2);
    unsigned need = out2[1];

    int tid = threadIdx.x, lane = tid & 63, w = tid >> 6;
    const unsigned long long* erow = ws->eqmask[c];
    unsigned long long* mrow = ws->u.mask[c];
    unsigned long long e0 = erow[2 * tid], e1 = erow[2 * tid + 1];
    unsigned pc0 = (unsigned)__popcll(e0), pc1 = (unsigned)__popcll(e1);
    unsigned cnt = pc0 + pc1;
    unsigned isc = cnt;
    #pragma unroll
    for (int d = 1; d < 64; d <<= 1) {
        unsigned o = __shfl_up(isc, (unsigned)d, 64);
        if (lane >= d) isc += o;
    }
    if (lane == 63) wsum[w] = isc;
    __syncthreads();
    unsigned wpre = 0;
    #pragma unroll
    for (int j = 0; j < 16; ++j) wpre += (j < w) ? wsum[j] : 0u;
    unsigned prev = wpre + isc - cnt;
    #pragma unroll
    for (int half = 0; half < 2; ++half) {
        unsigned long long e = half ? e1 : e0;
        unsigned pc = half ? pc1 : pc0;
        unsigned p  = half ? prev + pc0 : prev;
        if (pc > 0 && p < need) {
            unsigned keep = need - p;
            if (keep > pc) keep = pc;
            unsigned long long sel;
            if (keep == pc) sel = e;
            else {
                sel = 0ull;
                unsigned long long m = e;
                for (unsigned i = 0; i < keep; ++i) {
                    unsigned long long lsb = m & (~m + 1ull);
                    sel |= lsb;
                    m ^= lsb;
                }
            }
            mrow[2 * tid + half] |= sel;
        }
    }
}

// ================================================================ kernel D
// Final weighted sum; last-arriving block writes the output (saves k_write).
__global__ __launch_bounds__(640) void k_final3(const float* __restrict__ pred,
                                                const float* __restrict__ tgt,
                                                const float* __restrict__ rnd,
                                                Ws* __restrict__ ws,
                                                float* __restrict__ out) {
    int tid = threadIdx.x;
    long tile0 = (long)blockIdx.x * 5120;
    int  c0    = (tid * 4) % 40;
    float drate[4], majl[4], minl[4], wh[4], we[4];
    int hf[4], mp[4];
    #pragma unroll
    for (int u = 0; u < 4; ++u) {
        int c = c0 + u;
        drate[u] = ws->drate[c]; majl[u] = ws->majl[c]; minl[u] = ws->minl[c];
        wh[u] = ws->w_hard[c];   we[u] = ws->w_easy[c];
        hf[u] = ws->hardf[c];    mp[u] = ws->minpos[c];
    }
    double acc = 0.0;
    #pragma unroll
    for (int j = 0; j < 2; ++j) {
        long i = tile0 + j * 2560 + tid * 4;
        const float4 p  = *(const float4*)(pred + i);
        const float4 t  = *(const float4*)(tgt + i);
        const float4 rr = *(const float4*)(rnd + i);
        int b = (int)(i / 40);
        int wsh = b >> 6, bit = b & 63;
        #pragma unroll
        for (int u = 0; u < 4; ++u) {
            float pu = (&p.x)[u], tu = (&t.x)[u], ru = (&rr.x)[u];
            float bce, g;
            bce_g(pu, tu, bce, g);
            float w;
            if (hf[u]) {
                w = (tu == majl[u]) ? wh[u] : 1.0f;
            } else {
                bool dropped = (ws->u.mask[c0 + u][wsh] >> bit) & 1ull;
                w = dropped ? 0.0f : ((tu == minl[u] && mp[u]) ? we[u] : 1.0f);
            }
            if (g >= 0.8f && g < 1.000001f && ru > drate[u]) w = 0.0f;
            acc += (double)(bce * w);
        }
    }
    __shared__ double sd[640];
    sd[tid] = acc;
    __syncthreads();
    for (int s = 320; s >= 5; s >>= 1) {
        if (tid < s) sd[tid] += sd[tid + s];
        __syncthreads();
    }
    if (tid == 0) {
        double v = sd[0] + sd[1] + sd[2] + sd[3] + sd[4];
        atomicAdd(&ws->acc, v);
        __threadfence();
        unsigned t = atomicAdd(&ws->done, 1u);
        if (t == (unsigned)(NBLK - 1)) {
            double total = atomicAdd(&ws->acc, 0.0);   // coherent read
            out[0] = (float)(total / (double)NTOT);
        }
    }
}

// ================================================================ round-1
// fallback (ws too small)
__global__ void k_colreduce(const float* __restrict__ pred,
                            const float* __restrict__ tgt,
                            Ws* __restrict__ ws) {
    __shared__ float sl[CN];
    __shared__ int   sp[CN];
    int tid = threadIdx.x;
    if (tid < CN) { sl[tid] = 0.0f; sp[tid] = 0; }
    __syncthreads();
    int stride = gridDim.x * blockDim.x;
    for (int i = blockIdx.x * blockDim.x + tid; i < NTOT; i += stride) {
        int c = i % CN;
        float p = pred[i], t = tgt[i];
        atomicAdd(&sl[c], bce_f(p, t));
        if (t != 0.0f) atomicAdd(&sp[c], 1);
    }
    __syncthreads();
    if (tid < CN) {
        atomicAdd(&ws->lossc[tid], (double)sl[tid]);
        atomicAdd(&ws->posc[tid], sp[tid]);
    }
}

__global__ __launch_bounds__(1024) void k_params(const float* __restrict__ hard_rand,
                                                 const float* __restrict__ pos_prop,
                                                 Ws* __restrict__ ws) {
    int tid = threadIdx.x;
    __shared__ double lns[CN];
    __shared__ double smn, smx;
    if (tid < CN) lns[tid] = log10(1.0 + ws->lossc[tid]);
    __syncthreads();
    if (tid == 0) {
        double a = lns[0], b = lns[0];
        for (int i = 1; i < CN; i++) { a = fmin(a, lns[i]); b = fmax(b, lns[i]); }
        smn = a; smx = b;
    }
    __syncthreads();
    if (tid < CN) {
        int c = tid;
        double norm = 5.0 - 10.0 * (lns[c] - smn) / (smx - smn);
        float drate = (float)(1.0 / (1.0 + exp(-norm)));
        float Bf = (float)BN;
        float pos_sum = (float)ws->posc[c];
        float neg_sum = Bf - pos_sum;
        float bal_pos = pos_prop[c] * Bf;
        float bal_neg = Bf - bal_pos;
        bool pos_gt = pos_sum > bal_pos;
        bool neg_gt = neg_sum > bal_neg;
        float balance = pos_gt ? bal_pos : (neg_gt ? bal_neg : 0.0f);
        float dnum_f  = pos_gt ? (pos_sum - bal_pos)
                               : (neg_gt ? (neg_sum - bal_neg) : 0.0f);
        int   kdrop   = (int)floorf(dnum_f);
        float majl = pos_gt ? 1.0f : 0.0f;
        float minl = neg_gt ? 1.0f : 0.0f;
        float maj_cnt = (majl == 1.0f) ? pos_sum : neg_sum;
        float min_cnt = (minl == 1.0f) ? pos_sum : neg_sum;
        ws->drate[c]  = drate;
        ws->majl[c]   = majl;
        ws->minl[c]   = minl;
        ws->w_hard[c] = balance / fmaxf(maj_cnt, 1.0f);
        ws->w_easy[c] = (Bf - balance) / fmaxf(min_cnt, 1.0f);
        ws->hardf[c]  = (hard_rand[c] > drate) ? 1 : 0;
        ws->kdrop[c]  = kdrop;
        ws->minpos[c] = (min_cnt > 0.0f) ? 1 : 0;
    }
}

__global__ __launch_bounds__(1024) void k_select(const float* __restrict__ pred,
                                                 const float* __restrict__ tgt,
                                                 Ws* __restrict__ ws) {
    int c   = blockIdx.x;
    int tid = threadIdx.x;
    int k   = ws->kdrop[c];
    bool easy = (ws->hardf[c] == 0);
    unsigned long long* mrow = ws->u.mask[c];
    if (k <= 0 || !easy) {
        for (int i = tid; i < MASKW; i += 1024) mrow[i] = 0ull;
        return;
    }
    float majl = ws->majl[c];
    __shared__ unsigned h[256];
    __shared__ unsigned cum[256];
    __shared__ unsigned sh_sel, sh_krem;
    unsigned prefix = 0;
    unsigned krem   = (unsigned)k;
    for (int level = 0; level < 4; ++level) {
        int shift = 24 - 8 * level;
        for (int i = tid; i < 256; i += 1024) h[i] = 0;
        __syncthreads();
        for (int b = tid; b < BN; b += 1024) {
            float t = tgt[b * CN + c];
            if (t == majl) {
                unsigned bits = __float_as_uint(g_f(pred[b * CN + c], t));
                bool ok = (level == 0) || ((bits >> (shift + 8)) == prefix);
                if (ok) atomicAdd(&h[(bits >> shift) & 0xFFu], 1u);
            }
        }
        __syncthreads();
        if (tid < 256) cum[tid] = h[tid];
        __syncthreads();
        for (int off = 1; off < 256; off <<= 1) {
            unsigned v = 0;
            if (tid < 256 && tid >= off) v = cum[tid - off];
            __syncthreads();
            if (tid < 256 && tid >= off) cum[tid] += v;
            __syncthreads();
        }
        if (tid < 256) {
            unsigned prev = (tid == 0) ? 0u : cum[tid - 1];
            if (cum[tid] >= krem && prev < krem) {
                sh_sel  = (unsigned)tid;
                sh_krem = krem - prev;
            }
        }
        __syncthreads();
        prefix = (prefix << 8) | sh_sel;
        krem   = sh_krem;
        __syncthreads();
    }
    unsigned T    = prefix;
    unsigned need = krem;
    __shared__ unsigned wcnt[16];
    unsigned base = 0;
    int lane = tid & 63, wid = tid >> 6;
    for (int chunk = 0; chunk < BN / 1024; ++chunk) {
        int b = chunk * 1024 + tid;
        float t = tgt[b * CN + c];
        bool ismaj = (t == majl);
        unsigned bits = 0xFFFFFFFFu;
        if (ismaj) bits = __float_as_uint(g_f(pred[b * CN + c], t));
        bool lt = ismaj && (bits < T);
        bool eq = ismaj && (bits == T);
        unsigned long long bal = __ballot(eq);
        if (lane == 0) wcnt[wid] = (unsigned)__popcll(bal);
        __syncthreads();
        unsigned woff = 0, tot = 0;
        for (int w = 0; w < 16; ++w) {
            unsigned v = wcnt[w];
            if (w < wid) woff += v;
            tot += v;
        }
        unsigned long long lanemask = (lane == 0) ? 0ull : ((~0ull) >> (64 - lane));
        unsigned myrank = base + woff + (unsigned)__popcll(bal & lanemask);
        bool dropped = lt || (eq && myrank < need);
        unsigned long long bd = __ballot(dropped);
        if (lane == 0) mrow[chunk * 16 + wid] = bd;
        base += tot;
        __syncthreads();
    }
}

__global__ void k_final(const float* __restrict__ pred,
                        const float* __restrict__ tgt,
                        const float* __restrict__ rnd,
                        Ws* __restrict__ ws) {
    __shared__ double sdata[256];
    double acc = 0.0;
    int stride = gridDim.x * blockDim.x;
    for (int i = blockIdx.x * blockDim.x + threadIdx.x; i < NTOT; i += stride) {
        int b = i / CN;
        int c = i - b * CN;
        float p = pred[i], t = tgt[i], r = rnd[i];
        float bce = bce_f(p, t);
        float g   = g_f(p, t);
        float w;
        if (ws->hardf[c]) {
            w = (t == ws->majl[c]) ? ws->w_hard[c] : 1.0f;
        } else {
            bool dropped = (ws->u.mask[c][b >> 6] >> (b & 63)) & 1ull;
            if (dropped) w = 0.0f;
            else w = ((t == ws->minl[c]) && ws->minpos[c]) ? ws->w_easy[c] : 1.0f;
        }
        if ((g >= 0.8f) && (g < 1.000001f) && (r > ws->drate[c])) w = 0.0f;
        acc += (double)(bce * w);
    }
    sdata[threadIdx.x] = acc;
    __syncthreads();
    for (int s = blockDim.x / 2; s > 0; s >>= 1) {
        if (threadIdx.x < s) sdata[threadIdx.x] += sdata[threadIdx.x + s];
        __syncthreads();
    }
    if (threadIdx.x == 0) atomicAdd(&ws->acc, sdata[0]);
}

__global__ void k_write(Ws* __restrict__ ws, float* __restrict__ out) {
    out[0] = (float)(ws->acc / (double)NTOT);
}

extern "C" void kernel_launch(void* const* d_in, const int* in_sizes, int n_in,
                              void* d_out, int out_size, void* d_ws, size_t ws_size,
                              hipStream_t stream) {
    const float* pred      = (const float*)d_in[0];
    const float* tgt       = (const float*)d_in[1];
    const float* rnd       = (const float*)d_in[2];
    const float* hard_rand = (const float*)d_in[3];
    const float* pos_prop  = (const float*)d_in[4];
    Ws* ws = (Ws*)d_ws;

    if (ws_size >= sizeof(Ws)) {
        hipMemsetAsync(d_ws, 0, offsetof(Ws, lossc), stream);   // acc+done+ghists
        k_fuse  <<<NBLK, 640, 0, stream>>>(pred, tgt, ws);
        k_sel0  <<<CN * NCHUNK, 1024, 0, stream>>>(hard_rand, pos_prop, ws);
        k_hist1 <<<CN * NCHUNK, 1024, 0, stream>>>(ws);
        k_hist2 <<<CN * NCHUNK, 1024, 0, stream>>>(ws);
        k_mask  <<<CN * NCHUNK, 1024, 0, stream>>>(ws);
        k_tie   <<<CN, 1024, 0, stream>>>(ws);
        k_final3<<<NBLK, 640, 0, stream>>>(pred, tgt, rnd, ws, (float*)d_out);
    } else {
        hipMemsetAsync(d_ws, 0, offsetof(Ws, drate), stream);
        k_colreduce<<<2048, 256, 0, stream>>>(pred, tgt, ws);
        k_params<<<1, 1024, 0, stream>>>(hard_rand, pos_prop, ws);
        k_select<<<CN, 1024, 0, stream>>>(pred, tgt, ws);
        k_final <<<2048, 256, 0, stream>>>(pred, tgt, rnd, ws);
        k_write <<<1, 1, 0, stream>>>(ws, (float*)d_out);
    }
}

// Round 8
// 201.091 us; speedup vs baseline: 4.9607x; 1.0044x over previous
//
#include <hip/hip_runtime.h>
#include <hip/hip_bf16.h>
#include <math.h>
#include <stddef.h>

#define BN 131072
#define CN 40
#define NTOT (BN * CN)
#define MASKW (BN / 64)   // 2048 uint64 words per column
#define NBLK 1024         // k_fuse / k_final3 grid
#define NCHUNK 8          // selection chunks per column
#define CROWS (BN / NCHUNK)   // 16384 rows per chunk

// Workspace layout. Zeroed region = [acc .. ghist2] (one memset).
// u.mask is union'd with k_fuse partials: fuse writes parts -> k_params reads
// -> k_mask overwrites mask.
struct Ws {
    double acc;
    unsigned done;
    unsigned pad0;
    unsigned ghist0[CN][4096];         // level-0 hist (digit = mk>>18, <=4064)
    unsigned ghist1[CN][1024];         // level-1 hist (digit = (mk>>8)&0x3FF)
    unsigned ghist2[CN][256];          // level-2 hist (digit = mk&0xFF)
    // ---- not zeroed below (fast path) ----
    double lossc[CN];                  // round-1 fallback only
    int    posc[CN];                   // round-1 fallback only
    float drate[CN];
    float majl[CN];
    float minl[CN];
    float w_hard[CN];
    float w_easy[CN];
    int   hardf[CN];
    int   kdrop[CN];
    int   minpos[CN];
    union {
        unsigned long long mask[CN][MASKW];                           // 640 KB
        struct { float lpart[CN][NBLK]; int ppart[CN][NBLK]; } parts; // 320 KB
    } u;
    unsigned long long eqmask[CN][MASKW];  // ==T ballot masks (640 KB)
    unsigned keys[CN][BN];                 // transposed packed (g_bits<<1)|t
};

__device__ __forceinline__ float bce_f(float x, float t) {
    float e = __expf(-fabsf(x));
    return fmaxf(x, 0.0f) + __logf(1.0f + e) - x * t;
}
__device__ __forceinline__ float g_f(float x, float t) {
    float e   = __expf(-fabsf(x));
    float inv = __builtin_amdgcn_rcpf(1.0f + e);
    float s   = (x >= 0.0f) ? inv : e * inv;
    return fabsf(s - t);
}
// fused fast version: one exp for both bce and g
__device__ __forceinline__ void bce_g(float x, float t, float& bce, float& g) {
    float e   = __expf(-fabsf(x));
    bce       = fmaxf(x, 0.0f) + __logf(1.0f + e) - x * t;
    float inv = __builtin_amdgcn_rcpf(1.0f + e);
    float s   = (x >= 0.0f) ? inv : e * inv;   // stable sigmoid
    g         = fabsf(s - t);
}
__device__ __forceinline__ unsigned masked_key(unsigned key, unsigned majb) {
    return ((key & 1u) == majb) ? (key >> 1) : 0xFFFFFFFFu;
}
__device__ __forceinline__ bool col_active(const Ws* ws, int c) {
    return (ws->kdrop[c] > 0) && (ws->hardf[c] == 0);
}

// Block-wide pick: first bin where cumulative count >= krem.
// 1024 threads, PER bins/thread. out2[0]=bin, out2[1]=krem-prefix(bin).
template<int PER, int NBINS>
__device__ __forceinline__ void scan_pick(const unsigned* __restrict__ gh,
                                          unsigned krem,
                                          unsigned* wsum /*[16]*/,
                                          unsigned* out2 /*[2]*/) {
    int tid = threadIdx.x, lane = tid & 63, w = tid >> 6;
    unsigned v[PER];
    unsigned s = 0;
    #pragma unroll
    for (int i = 0; i < PER; ++i) {
        int idx = tid * PER + i;
        v[i] = (idx < NBINS) ? gh[idx] : 0u;
        s += v[i];
    }
    unsigned isc = s;
    #pragma unroll
    for (int d = 1; d < 64; d <<= 1) {
        unsigned o = __shfl_up(isc, (unsigned)d, 64);
        if (lane >= d) isc += o;
    }
    if (lane == 63) wsum[w] = isc;
    __syncthreads();
    unsigned wpre = 0;
    #pragma unroll
    for (int j = 0; j < 16; ++j) wpre += (j < w) ? wsum[j] : 0u;
    unsigned inc = wpre + isc, prev = inc - s;
    if (prev < krem && inc >= krem) {
        unsigned cum = prev;
        #pragma unroll
        for (int i = 0; i < PER; ++i) {
            if (cum < krem && cum + v[i] >= krem) {
                out2[0] = (unsigned)(tid * PER + i);
                out2[1] = krem - cum;
            }
            cum += v[i];
        }
    }
    __syncthreads();
}

// ================================================================ kernel A
// Fused: per-column bce sum + pos count + LDS-tiled transpose of packed keys.
// XCD-swizzled tile mapping for L2-local selection reads.
__global__ __launch_bounds__(640) void k_fuse(const float* __restrict__ pred,
                                              const float* __restrict__ tgt,
                                              Ws* __restrict__ ws) {
    __shared__ unsigned shk[128 * 41];   // +1 pad kills stride-40 bank conflict
    __shared__ float sl[CN];
    __shared__ int   sp[CN];
    int tid = threadIdx.x;
    if (tid < CN) { sl[tid] = 0.0f; sp[tid] = 0; }
    __syncthreads();

    int  tile  = (blockIdx.x & 7) * 128 + (blockIdx.x >> 3);   // XCD swizzle
    long tile0 = (long)tile * 5120;
    int  c0    = (tid * 4) % 40;         // fixed 4 columns per thread
    float accl[4] = {0, 0, 0, 0};
    int   cntp[4] = {0, 0, 0, 0};

    #pragma unroll
    for (int j = 0; j < 2; ++j) {
        int e = j * 2560 + tid * 4;
        const float4 p = *(const float4*)(pred + tile0 + e);
        const float4 t = *(const float4*)(tgt + tile0 + e);
        int r = e / 40;
        #pragma unroll
        for (int u = 0; u < 4; ++u) {
            float pu = (&p.x)[u], tu = (&t.x)[u];
            float bce, g;
            bce_g(pu, tu, bce, g);
            accl[u] += bce;
            int tb = (tu != 0.0f) ? 1 : 0;
            cntp[u] += tb;
            shk[r * 41 + c0 + u] = (__float_as_uint(g) << 1) | (unsigned)tb;
        }
    }
    #pragma unroll
    for (int u = 0; u < 4; ++u) {
        atomicAdd(&sl[c0 + u], accl[u]);
        atomicAdd(&sp[c0 + u], cntp[u]);
    }
    __syncthreads();

    int w = tid / 128, r = tid % 128;
    int row0 = tile * 128;
    #pragma unroll
    for (int cc = 0; cc < 8; ++cc) {
        int c = w * 8 + cc;
        ws->keys[c][row0 + r] = shk[r * 41 + c];
    }
    if (tid < CN) {
        ws->u.parts.lpart[tid][blockIdx.x] = sl[tid];
        ws->u.parts.ppart[tid][blockIdx.x] = sp[tid];
    }
}

// ================================================================ kernel B
// Single block: reduce the per-block partials -> per-column params.
// Kernel boundary after k_fuse provides device-wide coherence (no G16 risk).
__global__ __launch_bounds__(1024) void k_params2(const float* __restrict__ hard_rand,
                                                  const float* __restrict__ pos_prop,
                                                  Ws* __restrict__ ws) {
    int tid = threadIdx.x;
    __shared__ double sred[CN][17];
    __shared__ int    spre[CN][17];
    __shared__ double lossv[CN];
    __shared__ int    posv[CN];
    __shared__ double lns[CN];
    __shared__ double smn, smx;
    if (tid < CN * 16) {
        int c = tid >> 4, j = tid & 15;
        double s = 0.0; int p = 0;
        for (int i = j; i < NBLK; i += 16) {
            s += (double)ws->u.parts.lpart[c][i];
            p += ws->u.parts.ppart[c][i];
        }
        sred[c][j] = s; spre[c][j] = p;
    }
    __syncthreads();
    if (tid < CN) {
        double s = 0.0; int p = 0;
        for (int j = 0; j < 16; ++j) { s += sred[tid][j]; p += spre[tid][j]; }
        lossv[tid] = s; posv[tid] = p;
        lns[tid] = log10(1.0 + s);
    }
    __syncthreads();
    if (tid == 0) {
        double a = lns[0], b = lns[0];
        for (int i = 1; i < CN; i++) { a = fmin(a, lns[i]); b = fmax(b, lns[i]); }
        smn = a; smx = b;
    }
    __syncthreads();
    if (tid < CN) {
        int c = tid;
        double norm = 5.0 - 10.0 * (lns[c] - smn) / (smx - smn);
        float drate = (float)(1.0 / (1.0 + exp(-norm)));   // BASE_RATE = 0
        float Bf = (float)BN;
        float pos_sum = (float)posv[c];
        float neg_sum = Bf - pos_sum;
        float bal_pos = pos_prop[c] * Bf;
        float bal_neg = Bf - bal_pos;
        bool pos_gt = pos_sum > bal_pos;
        bool neg_gt = neg_sum > bal_neg;
        float balance = pos_gt ? bal_pos : (neg_gt ? bal_neg : 0.0f);
        float dnum_f  = pos_gt ? (pos_sum - bal_pos)
                               : (neg_gt ? (neg_sum - bal_neg) : 0.0f);
        int   kdrop   = (int)floorf(dnum_f);
        float majl = pos_gt ? 1.0f : 0.0f;
        float minl = neg_gt ? 1.0f : 0.0f;
        float maj_cnt = (majl == 1.0f) ? pos_sum : neg_sum;
        float min_cnt = (minl == 1.0f) ? pos_sum : neg_sum;
        ws->drate[c]  = drate;
        ws->majl[c]   = majl;
        ws->minl[c]   = minl;
        ws->w_hard[c] = balance / fmaxf(maj_cnt, 1.0f);
        ws->w_easy[c] = (Bf - balance) / fmaxf(min_cnt, 1.0f);
        ws->hardf[c]  = (hard_rand[c] > drate) ? 1 : 0;
        ws->kdrop[c]  = kdrop;
        ws->minpos[c] = (min_cnt > 0.0f) ? 1 : 0;
    }
}

// ================================================================ kernel H0
// grid = CN*NCHUNK. LDS 4096-bin hist of mk>>18 over the chunk's majority
// elements, flushed with one global atomic per bin.
__global__ __launch_bounds__(1024) void k_hist0(Ws* __restrict__ ws) {
    int c = blockIdx.x >> 3, chunk = blockIdx.x & 7;
    if (!col_active(ws, c)) return;
    unsigned majb = (ws->majl[c] != 0.0f) ? 1u : 0u;
    const uint4* __restrict__ kc4 = (const uint4*)(ws->keys[c] + chunk * CROWS);
    __shared__ unsigned h[4096];
    int tid = threadIdx.x;
    for (int i = tid; i < 4096; i += 1024) h[i] = 0;
    __syncthreads();
    for (int b4 = tid; b4 < CROWS / 4; b4 += 1024) {
        uint4 kk = kc4[b4];
        unsigned ks[4] = {kk.x, kk.y, kk.z, kk.w};
        #pragma unroll
        for (int q = 0; q < 4; ++q)
            if ((ks[q] & 1u) == majb) atomicAdd(&h[(ks[q] >> 1) >> 18], 1u);
    }
    __syncthreads();
    for (int i = tid; i < 4096; i += 1024)
        if (h[i]) atomicAdd(&ws->ghist0[c][i], h[i]);
}

// ================================================================ kernel H1
__global__ __launch_bounds__(1024) void k_hist1(Ws* __restrict__ ws) {
    int c = blockIdx.x >> 3, chunk = blockIdx.x & 7;
    if (!col_active(ws, c)) return;
    __shared__ unsigned wsum[16];
    __shared__ unsigned out2[2];
    scan_pick<4, 4096>(ws->ghist0[c], (unsigned)ws->kdrop[c], wsum, out2);
    unsigned p0 = out2[0];
    unsigned majb = (ws->majl[c] != 0.0f) ? 1u : 0u;
    const uint4* __restrict__ kc4 = (const uint4*)(ws->keys[c] + chunk * CROWS);
    __shared__ unsigned h[1024];
    int tid = threadIdx.x;
    h[tid] = 0;
    __syncthreads();
    for (int b4 = tid; b4 < CROWS / 4; b4 += 1024) {
        uint4 kk = kc4[b4];
        unsigned ks[4] = {kk.x, kk.y, kk.z, kk.w};
        #pragma unroll
        for (int q = 0; q < 4; ++q)
            if ((ks[q] & 1u) == majb) {
                unsigned mk = ks[q] >> 1;
                if ((mk >> 18) == p0) atomicAdd(&h[(mk >> 8) & 0x3FFu], 1u);
            }
    }
    __syncthreads();
    if (h[tid]) atomicAdd(&ws->ghist1[c][tid], h[tid]);
}

// ================================================================ kernel H2
__global__ __launch_bounds__(1024) void k_hist2(Ws* __restrict__ ws) {
    int c = blockIdx.x >> 3, chunk = blockIdx.x & 7;
    if (!col_active(ws, c)) return;
    __shared__ unsigned wsum[16];
    __shared__ unsigned out2[2];
    scan_pick<4, 4096>(ws->ghist0[c], (unsigned)ws->kdrop[c], wsum, out2);
    unsigned p0 = out2[0], krem1 = out2[1];
    scan_pick<1, 1024>(ws->ghist1[c], krem1, wsum, out2);
    unsigned pp = (p0 << 10) | out2[0];
    unsigned majb = (ws->majl[c] != 0.0f) ? 1u : 0u;
    const uint4* __restrict__ kc4 = (const uint4*)(ws->keys[c] + chunk * CROWS);
    __shared__ unsigned h[256];
    int tid = threadIdx.x;
    if (tid < 256) h[tid] = 0;
    __syncthreads();
    for (int b4 = tid; b4 < CROWS / 4; b4 += 1024) {
        uint4 kk = kc4[b4];
        unsigned ks[4] = {kk.x, kk.y, kk.z, kk.w};
        #pragma unroll
        for (int q = 0; q < 4; ++q)
            if ((ks[q] & 1u) == majb) {
                unsigned mk = ks[q] >> 1;
                if ((mk >> 8) == pp) atomicAdd(&h[mk & 0xFFu], 1u);
            }
    }
    __syncthreads();
    if (tid < 256 && h[tid]) atomicAdd(&ws->ghist2[c][tid], h[tid]);
}

// ================================================================ kernel M
__global__ __launch_bounds__(1024) void k_mask(Ws* __restrict__ ws) {
    int c = blockIdx.x >> 3, chunk = blockIdx.x & 7;
    int tid = threadIdx.x;
    unsigned long long* mrow = ws->u.mask[c];
    if (!col_active(ws, c)) {
        if (tid < MASKW / NCHUNK) mrow[chunk * (MASKW / NCHUNK) + tid] = 0ull;
        return;
    }
    __shared__ unsigned wsum[16];
    __shared__ unsigned out2[2];
    scan_pick<4, 4096>(ws->ghist0[c], (unsigned)ws->kdrop[c], wsum, out2);
    unsigned p0 = out2[0], krem1 = out2[1];
    scan_pick<1, 1024>(ws->ghist1[c], krem1, wsum, out2);
    unsigned p1 = out2[0], krem2 = out2[1];
    scan_pick<1, 256>(ws->ghist2[c], krem2, wsum, out2);
    unsigned T = (p0 << 18) | (p1 << 8) | out2[0];

    unsigned majb = (ws->majl[c] != 0.0f) ? 1u : 0u;
    const unsigned* __restrict__ kc = ws->keys[c];
    unsigned long long* erow = ws->eqmask[c];
    int lane = tid & 63, w = tid >> 6;
    int base = chunk * CROWS;
    for (int it = 0; it < CROWS / 1024; ++it) {
        int b = base + it * 1024 + tid;
        unsigned m = masked_key(kc[b], majb);   // sentinel > T always
        unsigned long long blt = __ballot(m < T);
        unsigned long long beq = __ballot(m == T);
        if (lane == 0) {
            int word = (base >> 6) + it * 16 + w;
            mrow[word] = blt;
            erow[word] = beq;
        }
    }
}

// ================================================================ kernel Tie
__global__ __launch_bounds__(1024) void k_tie(Ws* __restrict__ ws) {
    int c = blockIdx.x;
    if (!col_active(ws, c)) return;
    __shared__ unsigned wsum[16];
    __shared__ unsigned out2[2];
    scan_pick<4, 4096>(ws->ghist0[c], (unsigned)ws->kdrop[c], wsum, out2);
    unsigned krem1 = out2[1];
    scan_pick<1, 1024>(ws->ghist1[c], krem1, wsum, out2);
    unsigned krem2 = out2[1];
    scan_pick<1, 256>(ws->ghist2[c], krem2, wsum, out2);
    unsigned need = out2[1];

    int tid = threadIdx.x, lane = tid & 63, w = tid >> 6;
    const unsigned long long* erow = ws->eqmask[c];
    unsigned long long* mrow = ws->u.mask[c];
    unsigned long long e0 = erow[2 * tid], e1 = erow[2 * tid + 1];
    unsigned pc0 = (unsigned)__popcll(e0), pc1 = (unsigned)__popcll(e1);
    unsigned cnt = pc0 + pc1;
    unsigned isc = cnt;
    #pragma unroll
    for (int d = 1; d < 64; d <<= 1) {
        unsigned o = __shfl_up(isc, (unsigned)d, 64);
        if (lane >= d) isc += o;
    }
    if (lane == 63) wsum[w] = isc;
    __syncthreads();
    unsigned wpre = 0;
    #pragma unroll
    for (int j = 0; j < 16; ++j) wpre += (j < w) ? wsum[j] : 0u;
    unsigned prev = wpre + isc - cnt;
    #pragma unroll
    for (int half = 0; half < 2; ++half) {
        unsigned long long e = half ? e1 : e0;
        unsigned pc = half ? pc1 : pc0;
        unsigned p  = half ? prev + pc0 : prev;
        if (pc > 0 && p < need) {
            unsigned keep = need - p;
            if (keep > pc) keep = pc;
            unsigned long long sel;
            if (keep == pc) sel = e;
            else {
                sel = 0ull;
                unsigned long long m = e;
                for (unsigned i = 0; i < keep; ++i) {
                    unsigned long long lsb = m & (~m + 1ull);
                    sel |= lsb;
                    m ^= lsb;
                }
            }
            mrow[2 * tid + half] |= sel;
        }
    }
}

// ================================================================ kernel D
// Final weighted sum. Block covers rows [bid*128, +128) => per column only
// 2 mask words; preload them (and params) into LDS to kill the scattered
// global reads (round-7 post-mortem: those were the latency bottleneck).
// Last-arriving block writes the output.
__global__ __launch_bounds__(640) void k_final3(const float* __restrict__ pred,
                                                const float* __restrict__ tgt,
                                                const float* __restrict__ rnd,
                                                Ws* __restrict__ ws,
                                                float* __restrict__ out) {
    __shared__ double sd[640];
    __shared__ unsigned long long smask[CN][2];
    __shared__ float sdrate[CN], smajl[CN], sminl[CN], swh[CN], swe[CN];
    __shared__ int shf[CN], smp[CN];
    int tid = threadIdx.x;
    if (tid < CN) {
        sdrate[tid] = ws->drate[tid]; smajl[tid] = ws->majl[tid];
        sminl[tid]  = ws->minl[tid];  swh[tid]  = ws->w_hard[tid];
        swe[tid]    = ws->w_easy[tid]; shf[tid] = ws->hardf[tid];
        smp[tid]    = ws->minpos[tid];
    }
    if (tid >= 64 && tid < 64 + 2 * CN) {          // wave 1: mask words
        int q = tid - 64;
        smask[q >> 1][q & 1] = ws->u.mask[q >> 1][blockIdx.x * 2 + (q & 1)];
    }
    __syncthreads();

    long tile0 = (long)blockIdx.x * 5120;
    int  c0    = (tid * 4) % 40;
    float drate[4], majl[4], minl[4], wh[4], we[4];
    int hf[4], mp[4];
    #pragma unroll
    for (int u = 0; u < 4; ++u) {
        int c = c0 + u;
        drate[u] = sdrate[c]; majl[u] = smajl[c]; minl[u] = sminl[c];
        wh[u] = swh[c];       we[u] = swe[c];
        hf[u] = shf[c];       mp[u] = smp[c];
    }
    double acc = 0.0;
    #pragma unroll
    for (int j = 0; j < 2; ++j) {
        long i = tile0 + j * 2560 + tid * 4;
        const float4 p  = *(const float4*)(pred + i);
        const float4 t  = *(const float4*)(tgt + i);
        const float4 rr = *(const float4*)(rnd + i);
        int b = (int)(i / 40);
        int bit = b & 63;
        #pragma unroll
        for (int u = 0; u < 4; ++u) {
            float pu = (&p.x)[u], tu = (&t.x)[u], ru = (&rr.x)[u];
            float bce, g;
            bce_g(pu, tu, bce, g);
            float w;
            if (hf[u]) {
                w = (tu == majl[u]) ? wh[u] : 1.0f;
            } else {
                bool dropped = (smask[c0 + u][j] >> bit) & 1ull;
                w = dropped ? 0.0f : ((tu == minl[u] && mp[u]) ? we[u] : 1.0f);
            }
            if (g >= 0.8f && g < 1.000001f && ru > drate[u]) w = 0.0f;
            acc += (double)(bce * w);
        }
    }
    sd[tid] = acc;
    __syncthreads();
    for (int s = 320; s >= 5; s >>= 1) {
        if (tid < s) sd[tid] += sd[tid + s];
        __syncthreads();
    }
    if (tid == 0) {
        double v = sd[0] + sd[1] + sd[2] + sd[3] + sd[4];
        atomicAdd(&ws->acc, v);
        __threadfence();
        unsigned t = atomicAdd(&ws->done, 1u);
        if (t == (unsigned)(NBLK - 1)) {
            double total = atomicAdd(&ws->acc, 0.0);   // coherent read
            out[0] = (float)(total / (double)NTOT);
        }
    }
}

// ================================================================ round-1
// fallback (ws too small)
__global__ void k_colreduce(const float* __restrict__ pred,
                            const float* __restrict__ tgt,
                            Ws* __restrict__ ws) {
    __shared__ float sl[CN];
    __shared__ int   sp[CN];
    int tid = threadIdx.x;
    if (tid < CN) { sl[tid] = 0.0f; sp[tid] = 0; }
    __syncthreads();
    int stride = gridDim.x * blockDim.x;
    for (int i = blockIdx.x * blockDim.x + tid; i < NTOT; i += stride) {
        int c = i % CN;
        float p = pred[i], t = tgt[i];
        atomicAdd(&sl[c], bce_f(p, t));
        if (t != 0.0f) atomicAdd(&sp[c], 1);
    }
    __syncthreads();
    if (tid < CN) {
        atomicAdd(&ws->lossc[tid], (double)sl[tid]);
        atomicAdd(&ws->posc[tid], sp[tid]);
    }
}

__global__ __launch_bounds__(1024) void k_params(const float* __restrict__ hard_rand,
                                                 const float* __restrict__ pos_prop,
                                                 Ws* __restrict__ ws) {
    int tid = threadIdx.x;
    __shared__ double lns[CN];
    __shared__ double smn, smx;
    if (tid < CN) lns[tid] = log10(1.0 + ws->lossc[tid]);
    __syncthreads();
    if (tid == 0) {
        double a = lns[0], b = lns[0];
        for (int i = 1; i < CN; i++) { a = fmin(a, lns[i]); b = fmax(b, lns[i]); }
        smn = a; smx = b;
    }
    __syncthreads();
    if (tid < CN) {
        int c = tid;
        double norm = 5.0 - 10.0 * (lns[c] - smn) / (smx - smn);
        float drate = (float)(1.0 / (1.0 + exp(-norm)));
        float Bf = (float)BN;
        float pos_sum = (float)ws->posc[c];
        float neg_sum = Bf - pos_sum;
        float bal_pos = pos_prop[c] * Bf;
        float bal_neg = Bf - bal_pos;
        bool pos_gt = pos_sum > bal_pos;
        bool neg_gt = neg_sum > bal_neg;
        float balance = pos_gt ? bal_pos : (neg_gt ? bal_neg : 0.0f);
        float dnum_f  = pos_gt ? (pos_sum - bal_pos)
                               : (neg_gt ? (neg_sum - bal_neg) : 0.0f);
        int   kdrop   = (int)floorf(dnum_f);
        float majl = pos_gt ? 1.0f : 0.0f;
        float minl = neg_gt ? 1.0f : 0.0f;
        float maj_cnt = (majl == 1.0f) ? pos_sum : neg_sum;
        float min_cnt = (minl == 1.0f) ? pos_sum : neg_sum;
        ws->drate[c]  = drate;
        ws->majl[c]   = majl;
        ws->minl[c]   = minl;
        ws->w_hard[c] = balance / fmaxf(maj_cnt, 1.0f);
        ws->w_easy[c] = (Bf - balance) / fmaxf(min_cnt, 1.0f);
        ws->hardf[c]  = (hard_rand[c] > drate) ? 1 : 0;
        ws->kdrop[c]  = kdrop;
        ws->minpos[c] = (min_cnt > 0.0f) ? 1 : 0;
    }
}

__global__ __launch_bounds__(1024) void k_select(const float* __restrict__ pred,
                                                 const float* __restrict__ tgt,
                                                 Ws* __restrict__ ws) {
    int c   = blockIdx.x;
    int tid = threadIdx.x;
    int k   = ws->kdrop[c];
    bool easy = (ws->hardf[c] == 0);
    unsigned long long* mrow = ws->u.mask[c];
    if (k <= 0 || !easy) {
        for (int i = tid; i < MASKW; i += 1024) mrow[i] = 0ull;
        return;
    }
    float majl = ws->majl[c];
    __shared__ unsigned h[256];
    __shared__ unsigned cum[256];
    __shared__ unsigned sh_sel, sh_krem;
    unsigned prefix = 0;
    unsigned krem   = (unsigned)k;
    for (int level = 0; level < 4; ++level) {
        int shift = 24 - 8 * level;
        for (int i = tid; i < 256; i += 1024) h[i] = 0;
        __syncthreads();
        for (int b = tid; b < BN; b += 1024) {
            float t = tgt[b * CN + c];
            if (t == majl) {
                unsigned bits = __float_as_uint(g_f(pred[b * CN + c], t));
                bool ok = (level == 0) || ((bits >> (shift + 8)) == prefix);
                if (ok) atomicAdd(&h[(bits >> shift) & 0xFFu], 1u);
            }
        }
        __syncthreads();
        if (tid < 256) cum[tid] = h[tid];
        __syncthreads();
        for (int off = 1; off < 256; off <<= 1) {
            unsigned v = 0;
            if (tid < 256 && tid >= off) v = cum[tid - off];
            __syncthreads();
            if (tid < 256 && tid >= off) cum[tid] += v;
            __syncthreads();
        }
        if (tid < 256) {
            unsigned prev = (tid == 0) ? 0u : cum[tid - 1];
            if (cum[tid] >= krem && prev < krem) {
                sh_sel  = (unsigned)tid;
                sh_krem = krem - prev;
            }
        }
        __syncthreads();
        prefix = (prefix << 8) | sh_sel;
        krem   = sh_krem;
        __syncthreads();
    }
    unsigned T    = prefix;
    unsigned need = krem;
    __shared__ unsigned wcnt[16];
    unsigned base = 0;
    int lane = tid & 63, wid = tid >> 6;
    for (int chunk = 0; chunk < BN / 1024; ++chunk) {
        int b = chunk * 1024 + tid;
        float t = tgt[b * CN + c];
        bool ismaj = (t == majl);
        unsigned bits = 0xFFFFFFFFu;
        if (ismaj) bits = __float_as_uint(g_f(pred[b * CN + c], t));
        bool lt = ismaj && (bits < T);
        bool eq = ismaj && (bits == T);
        unsigned long long bal = __ballot(eq);
        if (lane == 0) wcnt[wid] = (unsigned)__popcll(bal);
        __syncthreads();
        unsigned woff = 0, tot = 0;
        for (int w = 0; w < 16; ++w) {
            unsigned v = wcnt[w];
            if (w < wid) woff += v;
            tot += v;
        }
        unsigned long long lanemask = (lane == 0) ? 0ull : ((~0ull) >> (64 - lane));
        unsigned myrank = base + woff + (unsigned)__popcll(bal & lanemask);
        bool dropped = lt || (eq && myrank < need);
        unsigned long long bd = __ballot(dropped);
        if (lane == 0) mrow[chunk * 16 + wid] = bd;
        base += tot;
        __syncthreads();
    }
}

__global__ void k_final(const float* __restrict__ pred,
                        const float* __restrict__ tgt,
                        const float* __restrict__ rnd,
                        Ws* __restrict__ ws) {
    __shared__ double sdata[256];
    double acc = 0.0;
    int stride = gridDim.x * blockDim.x;
    for (int i = blockIdx.x * blockDim.x + threadIdx.x; i < NTOT; i += stride) {
        int b = i / CN;
        int c = i - b * CN;
        float p = pred[i], t = tgt[i], r = rnd[i];
        float bce = bce_f(p, t);
        float g   = g_f(p, t);
        float w;
        if (ws->hardf[c]) {
            w = (t == ws->majl[c]) ? ws->w_hard[c] : 1.0f;
        } else {
            bool dropped = (ws->u.mask[c][b >> 6] >> (b & 63)) & 1ull;
            if (dropped) w = 0.0f;
            else w = ((t == ws->minl[c]) && ws->minpos[c]) ? ws->w_easy[c] : 1.0f;
        }
        if ((g >= 0.8f) && (g < 1.000001f) && (r > ws->drate[c])) w = 0.0f;
        acc += (double)(bce * w);
    }
    sdata[threadIdx.x] = acc;
    __syncthreads();
    for (int s = blockDim.x / 2; s > 0; s >>= 1) {
        if (threadIdx.x < s) sdata[threadIdx.x] += sdata[threadIdx.x + s];
        __syncthreads();
    }
    if (threadIdx.x == 0) atomicAdd(&ws->acc, sdata[0]);
}

__global__ void k_write(Ws* __restrict__ ws, float* __restrict__ out) {
    out[0] = (float)(ws->acc / (double)NTOT);
}

extern "C" void kernel_launch(void* const* d_in, const int* in_sizes, int n_in,
                              void* d_out, int out_size, void* d_ws, size_t ws_size,
                              hipStream_t stream) {
    const float* pred      = (const float*)d_in[0];
    const float* tgt       = (const float*)d_in[1];
    const float* rnd       = (const float*)d_in[2];
    const float* hard_rand = (const float*)d_in[3];
    const float* pos_prop  = (const float*)d_in[4];
    Ws* ws = (Ws*)d_ws;

    if (ws_size >= sizeof(Ws)) {
        hipMemsetAsync(d_ws, 0, offsetof(Ws, lossc), stream);   // acc+done+ghists
        k_fuse   <<<NBLK, 640, 0, stream>>>(pred, tgt, ws);
        k_params2<<<1, 1024, 0, stream>>>(hard_rand, pos_prop, ws);
        k_hist0  <<<CN * NCHUNK, 1024, 0, stream>>>(ws);
        k_hist1  <<<CN * NCHUNK, 1024, 0, stream>>>(ws);
        k_hist2  <<<CN * NCHUNK, 1024, 0, stream>>>(ws);
        k_mask   <<<CN * NCHUNK, 1024, 0, stream>>>(ws);
        k_tie    <<<CN, 1024, 0, stream>>>(ws);
        k_final3 <<<NBLK, 640, 0, stream>>>(pred, tgt, rnd, ws, (float*)d_out);
    } else {
        hipMemsetAsync(d_ws, 0, offsetof(Ws, drate), stream);
        k_colreduce<<<2048, 256, 0, stream>>>(pred, tgt, ws);
        k_params<<<1, 1024, 0, stream>>>(hard_rand, pos_prop, ws);
        k_select<<<CN, 1024, 0, stream>>>(pred, tgt, ws);
        k_final <<<2048, 256, 0, stream>>>(pred, tgt, rnd, ws);
        k_write <<<1, 1, 0, stream>>>(ws, (float*)d_out);
    }
}